// Round 1
// baseline (561.527 us; speedup 1.0000x reference)
//
#include <hip/hip_runtime.h>

// ---------------- constants (problem shape) ----------------
#define B_   2
#define S_   2048
#define D_   1024
#define H_   16
#define DK_  64
#define DFF_ 4096
#define M_   (B_*S_)   // 4096 rows

typedef unsigned short u16;
typedef __attribute__((ext_vector_type(8))) short short8;
typedef __attribute__((ext_vector_type(4))) float floatx4;

// fp32 -> bf16 round-to-nearest-even
__device__ __forceinline__ u16 f2bf(float f) {
    union { float f; unsigned u; } v; v.f = f;
    unsigned r = v.u + 0x7fffu + ((v.u >> 16) & 1u);
    return (u16)(r >> 16);
}

// async global->LDS, 16B per lane. LDS dest must be wave-uniform base.
__device__ __forceinline__ void g2l16(const u16* g, u16* l) {
    __builtin_amdgcn_global_load_lds((const __attribute__((address_space(1))) void*)g,
                                     (__attribute__((address_space(3))) void*)l,
                                     16, 0, 0);
}

// ---------------- fp32 -> bf16 convert ----------------
__global__ __launch_bounds__(256) void cvt_f2b(const float* __restrict__ in,
                                               u16* __restrict__ out, int n4) {
    for (int i = blockIdx.x * blockDim.x + threadIdx.x; i < n4;
         i += gridDim.x * blockDim.x) {
        float4 v = reinterpret_cast<const float4*>(in)[i];
        ushort4 o;
        o.x = f2bf(v.x); o.y = f2bf(v.y); o.z = f2bf(v.z); o.w = f2bf(v.w);
        reinterpret_cast<ushort4*>(out)[i] = o;
    }
}

__global__ __launch_bounds__(256) void concat3(const float* __restrict__ a,
                                               const float* __restrict__ b,
                                               const float* __restrict__ c,
                                               float* __restrict__ o) {
    int i = blockIdx.x * 256 + threadIdx.x;   // 0..3071
    if (i < 3 * D_) {
        float v = (i < D_) ? a[i] : (i < 2 * D_) ? b[i - D_] : c[i - 2 * D_];
        o[i] = v;
    }
}

// ---------------- GEMM: C[M,N] = A[M,K] @ B[N,K]^T + bias ----------------
// m97 structure: 128x128 tile, BK=32, 4 waves (2x2), global_load_lds staging.
// EPI: 0 = bias, store bf16 ; 1 = bias, store fp32 ; 2 = bias+erf-GELU, store bf16
template <int EPI>
__global__ __launch_bounds__(256) void gemm_bt(const u16* __restrict__ A,
                                               const u16* __restrict__ Bw,
                                               const float* __restrict__ bias,
                                               float* __restrict__ Cf,
                                               u16* __restrict__ Cb,
                                               int N, int K) {
    __shared__ u16 sA[128 * 32];
    __shared__ u16 sB[128 * 32];
    const int tid = threadIdx.x;
    const int wid = tid >> 6, lane = tid & 63;
    const int lrow = lane & 15, lgrp = lane >> 4;
    const int m0 = blockIdx.x * 128, n0 = blockIdx.y * 128;
    const int wm = wid >> 1, wn = wid & 1;
    const int ar = lane >> 2, ac = lane & 3;   // staging: 16 rows x 4 chunks per wave-call

    floatx4 acc[4][4] = {};
    const u16* Ab = A + (size_t)m0 * K;
    const u16* Bb = Bw + (size_t)n0 * K;

    for (int k0 = 0; k0 < K; k0 += 32) {
#pragma unroll
        for (int i = 0; i < 2; i++) {
            int seg = wid * 2 + i;              // 0..7, wave-uniform
            int row = seg * 16 + ar;
            g2l16(Ab + (size_t)row * K + k0 + ac * 8, &sA[seg * 512]);
            g2l16(Bb + (size_t)row * K + k0 + ac * 8, &sB[seg * 512]);
        }
        __syncthreads();
        short8 af[4], bfr[4];
#pragma unroll
        for (int mi = 0; mi < 4; mi++)
            af[mi] = *reinterpret_cast<const short8*>(
                &sA[(wm * 64 + mi * 16 + lrow) * 32 + lgrp * 8]);
#pragma unroll
        for (int ni = 0; ni < 4; ni++)
            bfr[ni] = *reinterpret_cast<const short8*>(
                &sB[(wn * 64 + ni * 16 + lrow) * 32 + lgrp * 8]);
#pragma unroll
        for (int mi = 0; mi < 4; mi++)
#pragma unroll
            for (int ni = 0; ni < 4; ni++)
                acc[mi][ni] = __builtin_amdgcn_mfma_f32_16x16x32_bf16(
                    af[mi], bfr[ni], acc[mi][ni], 0, 0, 0);
        __syncthreads();
    }

#pragma unroll
    for (int mi = 0; mi < 4; mi++) {
        int row = m0 + wm * 64 + mi * 16 + lgrp * 4;
#pragma unroll
        for (int ni = 0; ni < 4; ni++) {
            int col = n0 + wn * 64 + ni * 16 + lrow;
            float bc = bias[col];
#pragma unroll
            for (int j = 0; j < 4; j++) {
                float v = acc[mi][ni][j] + bc;
                if (EPI == 2) v = 0.5f * v * (1.0f + erff(v * 0.70710678118654752f));
                if (EPI == 1)
                    Cf[(size_t)(row + j) * N + col] = v;
                else
                    Cb[(size_t)(row + j) * N + col] = f2bf(v);
            }
        }
    }
}

// ---------------- flash attention ----------------
// QKV packed [M][3072] bf16 (q|k|v per row). One block = (b,h) x 64 q-rows.
// 4 waves x 16 q-rows. KV tiles of 64. Output cv bf16 [M][1024].
__global__ __launch_bounds__(256) void attn_kernel(const u16* __restrict__ QKV,
                                                   const int* __restrict__ mask,
                                                   u16* __restrict__ O) {
    const int SD = 3 * D_;                     // 3072 row stride
    __shared__ u16 kt[64][72];                 // [kj][d]   (+8 pad)
    __shared__ u16 vt[64][72];                 // [d][kj]   transposed
    __shared__ u16 pt[4][16][72];              // per-wave P tile

    const int qt = blockIdx.x, bh = blockIdx.y;
    const int b = bh >> 4, h = bh & 15;
    const int tid = threadIdx.x, wid = tid >> 6, lane = tid & 63;
    const int lrow = lane & 15, lgrp = lane >> 4;

    const u16* Qp = QKV + h * DK_;
    const u16* Kp = QKV + D_ + h * DK_;
    const u16* Vp = QKV + 2 * D_ + h * DK_;

    const int qr = qt * 64 + wid * 16 + lrow;
    const u16* qrow = Qp + (size_t)(b * S_ + qr) * SD;
    short8 aq0 = *reinterpret_cast<const short8*>(qrow + lgrp * 8);
    short8 aq1 = *reinterpret_cast<const short8*>(qrow + 32 + lgrp * 8);

    floatx4 accO[4] = {};
    float mrun[4], lrun[4];
#pragma unroll
    for (int j = 0; j < 4; j++) { mrun[j] = -1e30f; lrun[j] = 0.f; }

    for (int kv0 = 0; kv0 < S_; kv0 += 64) {
        // stage K (row-major) and V (transposed)
#pragma unroll
        for (int ci = 0; ci < 2; ci++) {
            int chunk = tid + 256 * ci;        // 0..511
            int r = chunk >> 3, c = chunk & 7;
            const u16* kp = Kp + (size_t)(b * S_ + kv0 + r) * SD + c * 8;
            *reinterpret_cast<short8*>(&kt[r][c * 8]) =
                *reinterpret_cast<const short8*>(kp);
            const u16* vp = Vp + (size_t)(b * S_ + kv0 + r) * SD + c * 8;
            short8 vv = *reinterpret_cast<const short8*>(vp);
#pragma unroll
            for (int i = 0; i < 8; i++) vt[c * 8 + i][r] = (u16)vv[i];
        }
        __syncthreads();

        // QK^T : 4 ni-tiles x (K=64 as 2 MFMA)
        floatx4 sc[4];
#pragma unroll
        for (int ni = 0; ni < 4; ni++) {
            short8 bk0 = *reinterpret_cast<const short8*>(&kt[ni * 16 + lrow][lgrp * 8]);
            short8 bk1 = *reinterpret_cast<const short8*>(&kt[ni * 16 + lrow][32 + lgrp * 8]);
            floatx4 z = {0.f, 0.f, 0.f, 0.f};
            z = __builtin_amdgcn_mfma_f32_16x16x32_bf16(aq0, bk0, z, 0, 0, 0);
            z = __builtin_amdgcn_mfma_f32_16x16x32_bf16(aq1, bk1, z, 0, 0, 0);
            sc[ni] = z;
        }

        // scale + mask (replace with -1e9 like the reference)
        float pm[4][4];
#pragma unroll
        for (int ni = 0; ni < 4; ni++) {
            bool valid = mask[b * S_ + kv0 + ni * 16 + lrow] != 0;
#pragma unroll
            for (int j = 0; j < 4; j++)
                pm[ni][j] = valid ? sc[ni][j] * 0.125f : -1e9f;
        }

        // online softmax per row (row = lgrp*4+j, cols spread over 16 lanes x 4 ni)
        float fac[4];
#pragma unroll
        for (int j = 0; j < 4; j++) {
            float m = fmaxf(fmaxf(pm[0][j], pm[1][j]), fmaxf(pm[2][j], pm[3][j]));
            m = fmaxf(m, __shfl_xor(m, 1, 64));
            m = fmaxf(m, __shfl_xor(m, 2, 64));
            m = fmaxf(m, __shfl_xor(m, 4, 64));
            m = fmaxf(m, __shfl_xor(m, 8, 64));
            float mn = fmaxf(mrun[j], m);
            fac[j] = __expf(mrun[j] - mn);
            mrun[j] = mn;
            float s = 0.f;
#pragma unroll
            for (int ni = 0; ni < 4; ni++) {
                float p = __expf(pm[ni][j] - mn);
                pm[ni][j] = p; s += p;
            }
            s += __shfl_xor(s, 1, 64);
            s += __shfl_xor(s, 2, 64);
            s += __shfl_xor(s, 4, 64);
            s += __shfl_xor(s, 8, 64);
            lrun[j] = lrun[j] * fac[j] + s;
        }
#pragma unroll
        for (int nd = 0; nd < 4; nd++) {
            floatx4 t = accO[nd];
            t[0] *= fac[0]; t[1] *= fac[1]; t[2] *= fac[2]; t[3] *= fac[3];
            accO[nd] = t;
        }

        // P -> LDS (bf16), then PV
#pragma unroll
        for (int ni = 0; ni < 4; ni++)
#pragma unroll
            for (int j = 0; j < 4; j++)
                pt[wid][lgrp * 4 + j][ni * 16 + lrow] = f2bf(pm[ni][j]);
        __syncthreads();

        short8 ap0 = *reinterpret_cast<const short8*>(&pt[wid][lrow][lgrp * 8]);
        short8 ap1 = *reinterpret_cast<const short8*>(&pt[wid][lrow][32 + lgrp * 8]);
#pragma unroll
        for (int nd = 0; nd < 4; nd++) {
            short8 bv0 = *reinterpret_cast<const short8*>(&vt[nd * 16 + lrow][lgrp * 8]);
            short8 bv1 = *reinterpret_cast<const short8*>(&vt[nd * 16 + lrow][32 + lgrp * 8]);
            accO[nd] = __builtin_amdgcn_mfma_f32_16x16x32_bf16(ap0, bv0, accO[nd], 0, 0, 0);
            accO[nd] = __builtin_amdgcn_mfma_f32_16x16x32_bf16(ap1, bv1, accO[nd], 0, 0, 0);
        }
        __syncthreads();
    }

    // epilogue: O = accO / l
#pragma unroll
    for (int nd = 0; nd < 4; nd++)
#pragma unroll
        for (int j = 0; j < 4; j++) {
            int r = lgrp * 4 + j;
            float v = accO[nd][j] / lrun[j];
            O[(size_t)(b * S_ + qt * 64 + wid * 16 + r) * D_ + h * DK_ + nd * 16 + lrow] =
                f2bf(v);
        }
}

// ---------------- residual + LayerNorm (torch: ddof=1, eps outside sqrt) ----------------
__global__ __launch_bounds__(256) void ln_kernel(const float* __restrict__ X,
                                                 const float* __restrict__ R,
                                                 const float* __restrict__ gam,
                                                 const float* __restrict__ bet,
                                                 float* __restrict__ outf,
                                                 u16* __restrict__ outb) {
    __shared__ float ws1[4], ws2[4];
    const int row = blockIdx.x, tid = threadIdx.x;
    const float4 x = reinterpret_cast<const float4*>(X + (size_t)row * D_)[tid];
    const float4 r = reinterpret_cast<const float4*>(R + (size_t)row * D_)[tid];
    float4 v; v.x = x.x + r.x; v.y = x.y + r.y; v.z = x.z + r.z; v.w = x.w + r.w;

    float s = v.x + v.y + v.z + v.w;
#pragma unroll
    for (int m = 32; m >= 1; m >>= 1) s += __shfl_xor(s, m, 64);
    if ((tid & 63) == 0) ws1[tid >> 6] = s;
    __syncthreads();
    float mean = (ws1[0] + ws1[1] + ws1[2] + ws1[3]) * (1.f / D_);

    float4 d; d.x = v.x - mean; d.y = v.y - mean; d.z = v.z - mean; d.w = v.w - mean;
    float q = d.x * d.x + d.y * d.y + d.z * d.z + d.w * d.w;
#pragma unroll
    for (int m = 32; m >= 1; m >>= 1) q += __shfl_xor(q, m, 64);
    if ((tid & 63) == 0) ws2[tid >> 6] = q;
    __syncthreads();
    float var = (ws2[0] + ws2[1] + ws2[2] + ws2[3]) * (1.f / (D_ - 1));
    float inv = 1.f / (sqrtf(var) + 1e-6f);

    const float4 g = reinterpret_cast<const float4*>(gam)[tid];
    const float4 bb = reinterpret_cast<const float4*>(bet)[tid];
    float4 o;
    o.x = g.x * d.x * inv + bb.x;
    o.y = g.y * d.y * inv + bb.y;
    o.z = g.z * d.z * inv + bb.z;
    o.w = g.w * d.w * inv + bb.w;
    if (outf) reinterpret_cast<float4*>(outf + (size_t)row * D_)[tid] = o;
    if (outb) {
        ushort4 ob;
        ob.x = f2bf(o.x); ob.y = f2bf(o.y); ob.z = f2bf(o.z); ob.w = f2bf(o.w);
        reinterpret_cast<ushort4*>(outb + (size_t)row * D_)[tid] = ob;
    }
}

// ---------------- launcher ----------------
extern "C" void kernel_launch(void* const* d_in, const int* in_sizes, int n_in,
                              void* d_out, int out_size, void* d_ws, size_t ws_size,
                              hipStream_t stream) {
    const float* x    = (const float*)d_in[0];
    const int*   mask = (const int*)d_in[1];
    const float* wq   = (const float*)d_in[2];
    const float* bq   = (const float*)d_in[3];
    const float* wk   = (const float*)d_in[4];
    const float* bk   = (const float*)d_in[5];
    const float* wv   = (const float*)d_in[6];
    const float* bv   = (const float*)d_in[7];
    const float* wo   = (const float*)d_in[8];
    const float* bo   = (const float*)d_in[9];
    const float* g1   = (const float*)d_in[10];
    const float* b1   = (const float*)d_in[11];
    const float* g2   = (const float*)d_in[12];
    const float* b2   = (const float*)d_in[13];
    const float* w1   = (const float*)d_in[14];
    const float* bf1  = (const float*)d_in[15];
    const float* w2   = (const float*)d_in[16];
    const float* bf2  = (const float*)d_in[17];
    float* out = (float*)d_out;

    char* ws = (char*)d_ws;
    size_t off = 0;
    auto alloc = [&](size_t bytes) -> void* {
        void* p = ws + off;
        off += (bytes + 255) & ~(size_t)255;
        return p;
    };
    u16*   xb    = (u16*)  alloc((size_t)M_ * D_ * 2);        // 8 MB
    u16*   wqkvb = (u16*)  alloc((size_t)3 * D_ * D_ * 2);    // 6 MB
    u16*   wob   = (u16*)  alloc((size_t)D_ * D_ * 2);        // 2 MB
    u16*   w1b   = (u16*)  alloc((size_t)DFF_ * D_ * 2);      // 8 MB
    u16*   w2b   = (u16*)  alloc((size_t)D_ * DFF_ * 2);      // 8 MB
    float* bqkv  = (float*)alloc((size_t)3 * D_ * 4);
    u16*   qkvb  = (u16*)  alloc((size_t)M_ * 3 * D_ * 2);    // 24 MB
    u16*   cvb   = (u16*)  alloc((size_t)M_ * D_ * 2);        // 8 MB
    float* projf = (float*)alloc((size_t)M_ * D_ * 4);        // 16 MB
    float* hdf   = (float*)alloc((size_t)M_ * D_ * 4);        // 16 MB
    u16*   hdb   = (u16*)  alloc((size_t)M_ * D_ * 2);        // 8 MB
    u16*   ff1b  = (u16*)  alloc((size_t)M_ * DFF_ * 2);      // 32 MB
    float* ff2f  = (float*)alloc((size_t)M_ * D_ * 4);        // 16 MB

    // bf16 conversions
    cvt_f2b<<<2048, 256, 0, stream>>>(x,  xb,    M_ * D_ / 4);
    cvt_f2b<<<1024, 256, 0, stream>>>(wq, wqkvb,             D_ * D_ / 4);
    cvt_f2b<<<1024, 256, 0, stream>>>(wk, wqkvb + D_ * D_,   D_ * D_ / 4);
    cvt_f2b<<<1024, 256, 0, stream>>>(wv, wqkvb + 2 * D_ * D_, D_ * D_ / 4);
    cvt_f2b<<<1024, 256, 0, stream>>>(wo, wob,   D_ * D_ / 4);
    cvt_f2b<<<2048, 256, 0, stream>>>(w1, w1b,   DFF_ * D_ / 4);
    cvt_f2b<<<2048, 256, 0, stream>>>(w2, w2b,   D_ * DFF_ / 4);
    concat3<<<12, 256, 0, stream>>>(bq, bk, bv, bqkv);

    // fused QKV projection: [4096,3072,1024]
    gemm_bt<0><<<dim3(M_ / 128, 3 * D_ / 128), 256, 0, stream>>>(
        xb, wqkvb, bqkv, nullptr, qkvb, 3 * D_, D_);

    // attention
    attn_kernel<<<dim3(S_ / 64, B_ * H_), 256, 0, stream>>>(qkvb, mask, cvb);

    // output projection: [4096,1024,1024] -> fp32
    gemm_bt<1><<<dim3(M_ / 128, D_ / 128), 256, 0, stream>>>(
        cvb, wob, bo, projf, nullptr, D_, D_);

    // residual + LN1 -> hdf (fp32), hdb (bf16)
    ln_kernel<<<M_, 256, 0, stream>>>(x, projf, g1, b1, hdf, hdb);

    // FFN1 + GELU: [4096,4096,1024] -> bf16
    gemm_bt<2><<<dim3(M_ / 128, DFF_ / 128), 256, 0, stream>>>(
        hdb, w1b, bf1, nullptr, ff1b, DFF_, D_);

    // FFN2: [4096,1024,4096] -> fp32
    gemm_bt<1><<<dim3(M_ / 128, D_ / 128), 256, 0, stream>>>(
        ff1b, w2b, bf2, ff2f, nullptr, D_, DFF_);

    // residual + LN2 -> out (fp32)
    ln_kernel<<<M_, 256, 0, stream>>>(hdf, ff2f, g2, b2, out, nullptr);
}

// Round 2
// 504.203 us; speedup vs baseline: 1.1137x; 1.1137x over previous
//
#include <hip/hip_runtime.h>

// ---------------- constants (problem shape) ----------------
#define B_   2
#define S_   2048
#define D_   1024
#define H_   16
#define DK_  64
#define DFF_ 4096
#define M_   (B_*S_)   // 4096 rows

typedef unsigned short u16;
typedef __attribute__((ext_vector_type(8))) short short8;
typedef __attribute__((ext_vector_type(4))) short bf16x4;
typedef __attribute__((ext_vector_type(4))) float floatx4;

// fp32 -> bf16 round-to-nearest-even
__device__ __forceinline__ u16 f2bf(float f) {
    union { float f; unsigned u; } v; v.f = f;
    unsigned r = v.u + 0x7fffu + ((v.u >> 16) & 1u);
    return (u16)(r >> 16);
}

// async global->LDS, 16B per lane. LDS dest must be wave-uniform base.
__device__ __forceinline__ void g2l16(const u16* g, u16* l) {
    __builtin_amdgcn_global_load_lds((const __attribute__((address_space(1))) void*)g,
                                     (__attribute__((address_space(3))) void*)l,
                                     16, 0, 0);
}

// generic shared pointer -> 32-bit LDS byte offset (low 32 bits of generic addr)
__device__ __forceinline__ unsigned lds_off(const void* p) {
    return (unsigned)(unsigned long long)p;
}

#define TRB16(dst, va, IMM)                                                    \
    asm volatile("ds_read_b64_tr_b16 %0, %1 offset:" #IMM                      \
                 : "=v"(dst) : "v"(va))

// ---------------- fp32 -> bf16 convert ----------------
__global__ __launch_bounds__(256) void cvt_f2b(const float* __restrict__ in,
                                               u16* __restrict__ out, int n4) {
    for (int i = blockIdx.x * blockDim.x + threadIdx.x; i < n4;
         i += gridDim.x * blockDim.x) {
        float4 v = reinterpret_cast<const float4*>(in)[i];
        ushort4 o;
        o.x = f2bf(v.x); o.y = f2bf(v.y); o.z = f2bf(v.z); o.w = f2bf(v.w);
        reinterpret_cast<ushort4*>(out)[i] = o;
    }
}

__global__ __launch_bounds__(256) void concat3(const float* __restrict__ a,
                                               const float* __restrict__ b,
                                               const float* __restrict__ c,
                                               float* __restrict__ o) {
    int i = blockIdx.x * 256 + threadIdx.x;   // 0..3071
    if (i < 3 * D_) {
        float v = (i < D_) ? a[i] : (i < 2 * D_) ? b[i - D_] : c[i - 2 * D_];
        o[i] = v;
    }
}

// ---------------- GEMM: C[M,N] = A[M,K] @ B[N,K]^T + bias ----------------
// m97 structure: 128x128 tile, BK=32, 4 waves (2x2), global_load_lds staging.
// EPI: 0 = bias, store bf16 ; 1 = bias, store fp32 ; 2 = bias+erf-GELU, store bf16
template <int EPI>
__global__ __launch_bounds__(256) void gemm_bt(const u16* __restrict__ A,
                                               const u16* __restrict__ Bw,
                                               const float* __restrict__ bias,
                                               float* __restrict__ Cf,
                                               u16* __restrict__ Cb,
                                               int N, int K) {
    __shared__ u16 sA[128 * 32];
    __shared__ u16 sB[128 * 32];
    const int tid = threadIdx.x;
    const int wid = tid >> 6, lane = tid & 63;
    const int lrow = lane & 15, lgrp = lane >> 4;

    // bijective XCD swizzle (m204): consecutive swz ids share the B-panel
    const int nbx = gridDim.x;
    const int nwg = nbx * gridDim.y;
    const int orig = blockIdx.y * nbx + blockIdx.x;
    const int qd = nwg >> 3, rr = nwg & 7, xc = orig & 7, oi = orig >> 3;
    const int swz = (xc < rr ? xc * (qd + 1) : rr * (qd + 1) + (xc - rr) * qd) + oi;
    const int m0 = (swz % nbx) * 128, n0 = (swz / nbx) * 128;

    const int wm = wid >> 1, wn = wid & 1;
    const int ar = lane >> 2, ac = lane & 3;

    floatx4 acc[4][4] = {};
    const u16* Ab = A + (size_t)m0 * K;
    const u16* Bb = Bw + (size_t)n0 * K;

    for (int k0 = 0; k0 < K; k0 += 32) {
#pragma unroll
        for (int i = 0; i < 2; i++) {
            int seg = wid * 2 + i;              // 0..7, wave-uniform
            int row = seg * 16 + ar;
            g2l16(Ab + (size_t)row * K + k0 + ac * 8, &sA[seg * 512]);
            g2l16(Bb + (size_t)row * K + k0 + ac * 8, &sB[seg * 512]);
        }
        __syncthreads();
        short8 af[4], bfr[4];
#pragma unroll
        for (int mi = 0; mi < 4; mi++)
            af[mi] = *reinterpret_cast<const short8*>(
                &sA[(wm * 64 + mi * 16 + lrow) * 32 + lgrp * 8]);
#pragma unroll
        for (int ni = 0; ni < 4; ni++)
            bfr[ni] = *reinterpret_cast<const short8*>(
                &sB[(wn * 64 + ni * 16 + lrow) * 32 + lgrp * 8]);
#pragma unroll
        for (int mi = 0; mi < 4; mi++)
#pragma unroll
            for (int ni = 0; ni < 4; ni++)
                acc[mi][ni] = __builtin_amdgcn_mfma_f32_16x16x32_bf16(
                    af[mi], bfr[ni], acc[mi][ni], 0, 0, 0);
        __syncthreads();
    }

#pragma unroll
    for (int mi = 0; mi < 4; mi++) {
        int row = m0 + wm * 64 + mi * 16 + lgrp * 4;
#pragma unroll
        for (int ni = 0; ni < 4; ni++) {
            int col = n0 + wn * 64 + ni * 16 + lrow;
            float bc = bias[col];
#pragma unroll
            for (int j = 0; j < 4; j++) {
                float v = acc[mi][ni][j] + bc;
                if (EPI == 2) v = 0.5f * v * (1.0f + erff(v * 0.70710678118654752f));
                if (EPI == 1)
                    Cf[(size_t)(row + j) * N + col] = v;
                else
                    Cb[(size_t)(row + j) * N + col] = f2bf(v);
            }
        }
    }
}

// ---------------- flash attention v2 ----------------
// QKV packed [M][3072] bf16. One block = (b,h) x 64 q-rows; 4 waves x 16 rows.
// K: linear [64][64] LDS, XOR-swizzled via pre-swizzled global source.
// V: tr-subtiled LDS layout, consumed via ds_read_b64_tr_b16.
// P: written transposed (subtiled) per wave, read back via tr reads.
// Double-buffered async staging with counted vmcnt(4) + raw s_barrier.
__global__ __launch_bounds__(256) void attn_kernel(const u16* __restrict__ QKV,
                                                   const int* __restrict__ mask,
                                                   u16* __restrict__ O) {
    const int SD = 3 * D_;                     // 3072 row stride
    __shared__ alignas(16) u16 ktL[2][4096];   // [buf][64 rows][64 d] (src-swizzled)
    __shared__ alignas(16) u16 vtL[2][4096];   // [buf] tr-subtiled V
    __shared__ alignas(16) u16 ptL[4][1024];   // per-wave P^T, tr-subtiled

    // XCD swizzle: nwg = 1024 (divisible by 8); same-bh blocks -> same XCD
    const int orig = blockIdx.y * gridDim.x + blockIdx.x;
    const int swz = (orig & 7) * 128 + (orig >> 3);
    const int qt = swz & 31, bh = swz >> 5;
    const int b = bh >> 4, h = bh & 15;

    const int tid = threadIdx.x, wid = tid >> 6, lane = tid & 63;
    const int lrow = lane & 15, lgrp = lane >> 4;

    const u16* Qp = QKV + h * DK_;
    const u16* Kp = QKV + D_ + h * DK_;
    const u16* Vp = QKV + 2 * D_ + h * DK_;

    // Q fragments (held in registers for the whole block)
    const int qr = qt * 64 + wid * 16 + lrow;
    const u16* qrow = Qp + (size_t)(b * S_ + qr) * SD;
    short8 aq0 = *reinterpret_cast<const short8*>(qrow + lgrp * 8);
    short8 aq1 = *reinterpret_cast<const short8*>(qrow + 32 + lgrp * 8);

    // per-thread staging source pointers (advance by 64*SD per tile)
    const u16* kq[2];
    const u16* vq[2];
#pragma unroll
    for (int i = 0; i < 2; i++) {
        int s = wid * 2 + i;
        int q8 = s * 64 + lane;                // dest/16B chunk index
        int krow = q8 >> 3, kcb = q8 & 7;
        kq[i] = Kp + (size_t)(b * S_ + krow) * SD + ((kcb ^ (krow & 7)) * 8);
        int o = s * 512 + lane * 8;            // dest u16 offset
        int vk = ((o >> 6) & 7) * 8 + ((o >> 9) & 1) * 4 + ((o >> 4) & 3);
        int vd = (o >> 10) * 16 + (o & 8);
        vq[i] = Vp + (size_t)(b * S_ + vk) * SD + vd;
    }

    auto issue = [&](int bufIdx) {
        u16* kb_ = ktL[bufIdx];
        u16* vb_ = vtL[bufIdx];
#pragma unroll
        for (int i = 0; i < 2; i++) {
            int s = wid * 2 + i;
            g2l16(kq[i], kb_ + s * 512);
            g2l16(vq[i], vb_ + s * 512);
            kq[i] += 64 * SD;
            vq[i] += 64 * SD;
        }
    };

    floatx4 accO[4] = {};
    float mrun[4], lrun[4];
#pragma unroll
    for (int j = 0; j < 4; j++) { mrun[j] = -1e30f; lrun[j] = 0.f; }

    const unsigned vpa = lds_off(ptL[wid]) + lane * 8;

    issue(0);
    int cur = 0;
    for (int t = 0; t < S_ / 64; t++) {
        const int kv0 = t * 64;
        if (t < S_ / 64 - 1) {
            issue(cur ^ 1);
            asm volatile("s_waitcnt vmcnt(4)" ::: "memory");
        } else {
            asm volatile("s_waitcnt vmcnt(0)" ::: "memory");
        }
        __builtin_amdgcn_s_barrier();
        asm volatile("" ::: "memory");

        const u16* ktc = ktL[cur];
        const unsigned vva = lds_off(vtL[cur]) + lane * 8;

        // mask for this tile
        int mk[4];
#pragma unroll
        for (int ni = 0; ni < 4; ni++)
            mk[ni] = mask[b * S_ + kv0 + ni * 16 + lrow];

        // ---- QK^T ----
        floatx4 sc[4];
        __builtin_amdgcn_s_setprio(1);
#pragma unroll
        for (int ni = 0; ni < 4; ni++) {
            int row = ni * 16 + lrow;
            int off0 = (row * 128 + lgrp * 16) ^ ((lrow & 7) << 4);
            int off1 = (row * 128 + (lgrp + 4) * 16) ^ ((lrow & 7) << 4);
            short8 bk0 = *reinterpret_cast<const short8*>((const char*)ktc + off0);
            short8 bk1 = *reinterpret_cast<const short8*>((const char*)ktc + off1);
            floatx4 z = {0.f, 0.f, 0.f, 0.f};
            z = __builtin_amdgcn_mfma_f32_16x16x32_bf16(aq0, bk0, z, 0, 0, 0);
            z = __builtin_amdgcn_mfma_f32_16x16x32_bf16(aq1, bk1, z, 0, 0, 0);
            sc[ni] = z;
        }
        __builtin_amdgcn_s_setprio(0);

        // scale + mask
        float pm[4][4];
#pragma unroll
        for (int ni = 0; ni < 4; ni++) {
            bool valid = mk[ni] != 0;
#pragma unroll
            for (int j = 0; j < 4; j++)
                pm[ni][j] = valid ? sc[ni][j] * 0.125f : -1e9f;
        }

        // online softmax (row q = lgrp*4+j; cols over 16 lanes x 4 ni)
        float fac[4];
#pragma unroll
        for (int j = 0; j < 4; j++) {
            float m = fmaxf(fmaxf(pm[0][j], pm[1][j]), fmaxf(pm[2][j], pm[3][j]));
            m = fmaxf(m, __shfl_xor(m, 1, 64));
            m = fmaxf(m, __shfl_xor(m, 2, 64));
            m = fmaxf(m, __shfl_xor(m, 4, 64));
            m = fmaxf(m, __shfl_xor(m, 8, 64));
            float mn = fmaxf(mrun[j], m);
            fac[j] = __expf(mrun[j] - mn);
            mrun[j] = mn;
            float s = 0.f;
#pragma unroll
            for (int ni = 0; ni < 4; ni++) {
                float p = __expf(pm[ni][j] - mn);
                pm[ni][j] = p; s += p;
            }
            s += __shfl_xor(s, 1, 64);
            s += __shfl_xor(s, 2, 64);
            s += __shfl_xor(s, 4, 64);
            s += __shfl_xor(s, 8, 64);
            lrun[j] = lrun[j] * fac[j] + s;
        }

        // ---- P^T -> per-wave LDS (subtiled for tr reads) ----
#pragma unroll
        for (int ni = 0; ni < 4; ni++) {
            bf16x4 pw;
#pragma unroll
            for (int j = 0; j < 4; j++) pw[j] = (short)f2bf(pm[ni][j]);
            int k = ni * 16 + lrow;
            int woff = (k >> 3) * 64 + ((k >> 2) & 1) * 512 + (k & 3) * 16 + lgrp * 4;
            *reinterpret_cast<bf16x4*>(ptL[wid] + woff) = pw;
        }
        asm volatile("s_waitcnt lgkmcnt(0)" ::: "memory");
        __builtin_amdgcn_sched_barrier(0);

        // ---- tr reads: P fragments + V fragments ----
        bf16x4 p0a, p0b, p1a, p1b;
        TRB16(p0a, vpa, 0);
        TRB16(p0b, vpa, 1024);
        TRB16(p1a, vpa, 512);
        TRB16(p1b, vpa, 1536);
        short8 bv0[4], bv1[4];
#pragma unroll
        for (int nd = 0; nd < 4; nd++) {
            unsigned a = vva + nd * 2048;
            bf16x4 t0, t1, t2, t3;
            TRB16(t0, a, 0);
            TRB16(t1, a, 1024);
            TRB16(t2, a, 512);
            TRB16(t3, a, 1536);
            bv0[nd] = __builtin_shufflevector(t0, t1, 0, 1, 2, 3, 4, 5, 6, 7);
            bv1[nd] = __builtin_shufflevector(t2, t3, 0, 1, 2, 3, 4, 5, 6, 7);
        }
        asm volatile("s_waitcnt lgkmcnt(0)" ::: "memory");
        __builtin_amdgcn_sched_barrier(0);
        short8 ap0 = __builtin_shufflevector(p0a, p0b, 0, 1, 2, 3, 4, 5, 6, 7);
        short8 ap1 = __builtin_shufflevector(p1a, p1b, 0, 1, 2, 3, 4, 5, 6, 7);

        // rescale + PV
#pragma unroll
        for (int nd = 0; nd < 4; nd++) {
            floatx4 tt = accO[nd];
            tt[0] *= fac[0]; tt[1] *= fac[1]; tt[2] *= fac[2]; tt[3] *= fac[3];
            accO[nd] = tt;
        }
        __builtin_amdgcn_s_setprio(1);
#pragma unroll
        for (int nd = 0; nd < 4; nd++) {
            accO[nd] = __builtin_amdgcn_mfma_f32_16x16x32_bf16(ap0, bv0[nd], accO[nd], 0, 0, 0);
            accO[nd] = __builtin_amdgcn_mfma_f32_16x16x32_bf16(ap1, bv1[nd], accO[nd], 0, 0, 0);
        }
        __builtin_amdgcn_s_setprio(0);

        asm volatile("" ::: "memory");
        __builtin_amdgcn_s_barrier();
        cur ^= 1;
    }

    // epilogue: O = accO / l
#pragma unroll
    for (int nd = 0; nd < 4; nd++)
#pragma unroll
        for (int j = 0; j < 4; j++) {
            int r = lgrp * 4 + j;
            float v = accO[nd][j] / lrun[j];
            O[(size_t)(b * S_ + qt * 64 + wid * 16 + r) * D_ + h * DK_ + nd * 16 + lrow] =
                f2bf(v);
        }
}

// ---------------- residual + LayerNorm (torch: ddof=1, eps outside sqrt) ----------------
__global__ __launch_bounds__(256) void ln_kernel(const float* __restrict__ X,
                                                 const float* __restrict__ R,
                                                 const float* __restrict__ gam,
                                                 const float* __restrict__ bet,
                                                 float* __restrict__ outf,
                                                 u16* __restrict__ outb) {
    __shared__ float ws1[4], ws2[4];
    const int row = blockIdx.x, tid = threadIdx.x;
    const float4 x = reinterpret_cast<const float4*>(X + (size_t)row * D_)[tid];
    const float4 r = reinterpret_cast<const float4*>(R + (size_t)row * D_)[tid];
    float4 v; v.x = x.x + r.x; v.y = x.y + r.y; v.z = x.z + r.z; v.w = x.w + r.w;

    float s = v.x + v.y + v.z + v.w;
#pragma unroll
    for (int m = 32; m >= 1; m >>= 1) s += __shfl_xor(s, m, 64);
    if ((tid & 63) == 0) ws1[tid >> 6] = s;
    __syncthreads();
    float mean = (ws1[0] + ws1[1] + ws1[2] + ws1[3]) * (1.f / D_);

    float4 d; d.x = v.x - mean; d.y = v.y - mean; d.z = v.z - mean; d.w = v.w - mean;
    float q = d.x * d.x + d.y * d.y + d.z * d.z + d.w * d.w;
#pragma unroll
    for (int m = 32; m >= 1; m >>= 1) q += __shfl_xor(q, m, 64);
    if ((tid & 63) == 0) ws2[tid >> 6] = q;
    __syncthreads();
    float var = (ws2[0] + ws2[1] + ws2[2] + ws2[3]) * (1.f / (D_ - 1));
    float inv = 1.f / (sqrtf(var) + 1e-6f);

    const float4 g = reinterpret_cast<const float4*>(gam)[tid];
    const float4 bb = reinterpret_cast<const float4*>(bet)[tid];
    float4 o;
    o.x = g.x * d.x * inv + bb.x;
    o.y = g.y * d.y * inv + bb.y;
    o.z = g.z * d.z * inv + bb.z;
    o.w = g.w * d.w * inv + bb.w;
    if (outf) reinterpret_cast<float4*>(outf + (size_t)row * D_)[tid] = o;
    if (outb) {
        ushort4 ob;
        ob.x = f2bf(o.x); ob.y = f2bf(o.y); ob.z = f2bf(o.z); ob.w = f2bf(o.w);
        reinterpret_cast<ushort4*>(outb + (size_t)row * D_)[tid] = ob;
    }
}

// ---------------- launcher ----------------
extern "C" void kernel_launch(void* const* d_in, const int* in_sizes, int n_in,
                              void* d_out, int out_size, void* d_ws, size_t ws_size,
                              hipStream_t stream) {
    const float* x    = (const float*)d_in[0];
    const int*   mask = (const int*)d_in[1];
    const float* wq   = (const float*)d_in[2];
    const float* bq   = (const float*)d_in[3];
    const float* wk   = (const float*)d_in[4];
    const float* bk   = (const float*)d_in[5];
    const float* wv   = (const float*)d_in[6];
    const float* bv   = (const float*)d_in[7];
    const float* wo   = (const float*)d_in[8];
    const float* bo   = (const float*)d_in[9];
    const float* g1   = (const float*)d_in[10];
    const float* b1   = (const float*)d_in[11];
    const float* g2   = (const float*)d_in[12];
    const float* b2   = (const float*)d_in[13];
    const float* w1   = (const float*)d_in[14];
    const float* bf1  = (const float*)d_in[15];
    const float* w2   = (const float*)d_in[16];
    const float* bf2  = (const float*)d_in[17];
    float* out = (float*)d_out;

    char* ws = (char*)d_ws;
    size_t off = 0;
    auto alloc = [&](size_t bytes) -> void* {
        void* p = ws + off;
        off += (bytes + 255) & ~(size_t)255;
        return p;
    };
    u16*   xb    = (u16*)  alloc((size_t)M_ * D_ * 2);
    u16*   wqkvb = (u16*)  alloc((size_t)3 * D_ * D_ * 2);
    u16*   wob   = (u16*)  alloc((size_t)D_ * D_ * 2);
    u16*   w1b   = (u16*)  alloc((size_t)DFF_ * D_ * 2);
    u16*   w2b   = (u16*)  alloc((size_t)D_ * DFF_ * 2);
    float* bqkv  = (float*)alloc((size_t)3 * D_ * 4);
    u16*   qkvb  = (u16*)  alloc((size_t)M_ * 3 * D_ * 2);
    u16*   cvb   = (u16*)  alloc((size_t)M_ * D_ * 2);
    float* projf = (float*)alloc((size_t)M_ * D_ * 4);
    float* hdf   = (float*)alloc((size_t)M_ * D_ * 4);
    u16*   hdb   = (u16*)  alloc((size_t)M_ * D_ * 2);
    u16*   ff1b  = (u16*)  alloc((size_t)M_ * DFF_ * 2);
    float* ff2f  = (float*)alloc((size_t)M_ * D_ * 4);

    // bf16 conversions
    cvt_f2b<<<2048, 256, 0, stream>>>(x,  xb,    M_ * D_ / 4);
    cvt_f2b<<<1024, 256, 0, stream>>>(wq, wqkvb,               D_ * D_ / 4);
    cvt_f2b<<<1024, 256, 0, stream>>>(wk, wqkvb + D_ * D_,     D_ * D_ / 4);
    cvt_f2b<<<1024, 256, 0, stream>>>(wv, wqkvb + 2 * D_ * D_, D_ * D_ / 4);
    cvt_f2b<<<1024, 256, 0, stream>>>(wo, wob,   D_ * D_ / 4);
    cvt_f2b<<<2048, 256, 0, stream>>>(w1, w1b,   DFF_ * D_ / 4);
    cvt_f2b<<<2048, 256, 0, stream>>>(w2, w2b,   D_ * DFF_ / 4);
    concat3<<<12, 256, 0, stream>>>(bq, bk, bv, bqkv);

    // fused QKV projection: [4096,3072,1024]
    gemm_bt<0><<<dim3(M_ / 128, 3 * D_ / 128), 256, 0, stream>>>(
        xb, wqkvb, bqkv, nullptr, qkvb, 3 * D_, D_);

    // attention
    attn_kernel<<<dim3(S_ / 64, B_ * H_), 256, 0, stream>>>(qkvb, mask, cvb);

    // output projection: [4096,1024,1024] -> fp32
    gemm_bt<1><<<dim3(M_ / 128, D_ / 128), 256, 0, stream>>>(
        cvb, wob, bo, projf, nullptr, D_, D_);

    // residual + LN1 -> hdf (fp32), hdb (bf16)
    ln_kernel<<<M_, 256, 0, stream>>>(x, projf, g1, b1, hdf, hdb);

    // FFN1 + GELU: [4096,4096,1024] -> bf16
    gemm_bt<2><<<dim3(M_ / 128, DFF_ / 128), 256, 0, stream>>>(
        hdb, w1b, bf1, nullptr, ff1b, DFF_, D_);

    // FFN2: [4096,1024,4096] -> fp32
    gemm_bt<1><<<dim3(M_ / 128, D_ / 128), 256, 0, stream>>>(
        ff1b, w2b, bf2, ff2f, nullptr, D_, DFF_);

    // residual + LN2 -> out (fp32)
    ln_kernel<<<M_, 256, 0, stream>>>(hdf, ff2f, g2, b2, out, nullptr);
}

// Round 3
// 480.368 us; speedup vs baseline: 1.1690x; 1.0496x over previous
//
#include <hip/hip_runtime.h>
#include <hip/hip_bf16.h>

// ---------------- constants (problem shape) ----------------
#define B_   2
#define S_   2048
#define D_   1024
#define H_   16
#define DK_  64
#define DFF_ 4096
#define M_   (B_*S_)   // 4096 rows

typedef unsigned short u16;
typedef __attribute__((ext_vector_type(8))) short short8;
typedef __attribute__((ext_vector_type(4))) short bf16x4;
typedef __attribute__((ext_vector_type(4))) float floatx4;

// fp32 -> bf16 round-to-nearest-even (manual, used in GEMM epilogue)
__device__ __forceinline__ u16 f2bf(float f) {
    union { float f; unsigned u; } v; v.f = f;
    unsigned r = v.u + 0x7fffu + ((v.u >> 16) & 1u);
    return (u16)(r >> 16);
}
// compiler path (emits v_cvt_pk_bf16_f32 for pairs)
__device__ __forceinline__ u16 f2bf_fast(float f) {
    __hip_bfloat16 h = __float2bfloat16(f);
    return *reinterpret_cast<u16*>(&h);
}

// async global->LDS, 16B per lane. LDS dest must be wave-uniform base.
__device__ __forceinline__ void g2l16(const u16* g, u16* l) {
    __builtin_amdgcn_global_load_lds((const __attribute__((address_space(1))) void*)g,
                                     (__attribute__((address_space(3))) void*)l,
                                     16, 0, 0);
}

__device__ __forceinline__ unsigned lds_off(const void* p) {
    return (unsigned)(unsigned long long)p;
}

#define TRB16(dst, va, IMM)                                                    \
    asm volatile("ds_read_b64_tr_b16 %0, %1 offset:" #IMM                      \
                 : "=v"(dst) : "v"(va))

// ---------------- fused fp32->bf16 conversion of x + all weights ----------------
// segments (float4 units): x 1048576 | wq 262144 | wk 262144 | wv 262144
//                          | wo 262144 | w1 1048576 | w2 1048576  = 4194304
__global__ __launch_bounds__(256) void cvt_all(
    const float* __restrict__ x,  const float* __restrict__ wq,
    const float* __restrict__ wk, const float* __restrict__ wv,
    const float* __restrict__ wo, const float* __restrict__ w1,
    const float* __restrict__ w2,
    u16* __restrict__ xb, u16* __restrict__ wqkvb, u16* __restrict__ wob,
    u16* __restrict__ w1b, u16* __restrict__ w2b) {
    for (int i = blockIdx.x * 256 + threadIdx.x; i < 4194304;
         i += gridDim.x * 256) {
        const float* s; u16* d; int off;
        if (i < 1048576)      { s = x;  d = xb;    off = i; }
        else if (i < 1310720) { s = wq; d = wqkvb; off = i - 1048576; }
        else if (i < 1572864) { s = wk; d = wqkvb + 1048576; off = i - 1310720; }
        else if (i < 1835008) { s = wv; d = wqkvb + 2097152; off = i - 1572864; }
        else if (i < 2097152) { s = wo; d = wob;   off = i - 1835008; }
        else if (i < 3145728) { s = w1; d = w1b;   off = i - 2097152; }
        else                  { s = w2; d = w2b;   off = i - 3145728; }
        float4 v = reinterpret_cast<const float4*>(s)[off];
        ushort4 o;
        o.x = f2bf(v.x); o.y = f2bf(v.y); o.z = f2bf(v.z); o.w = f2bf(v.w);
        reinterpret_cast<ushort4*>(d)[off] = o;
    }
}

// bias concat (3072) + mask->mbias (4096). grid 28x256
__global__ __launch_bounds__(256) void prep_misc(const float* __restrict__ bq,
                                                 const float* __restrict__ bk,
                                                 const float* __restrict__ bv,
                                                 const int* __restrict__ mask,
                                                 float* __restrict__ bqkv,
                                                 float* __restrict__ mbias) {
    int i = blockIdx.x * 256 + threadIdx.x;
    if (i < 3 * D_) {
        float v = (i < D_) ? bq[i] : (i < 2 * D_) ? bk[i - D_] : bv[i - 2 * D_];
        bqkv[i] = v;
    } else if (i < 3 * D_ + B_ * S_) {
        int k = i - 3 * D_;
        mbias[k] = (mask[k] == 0) ? -1e9f : 0.0f;
    }
}

// ---------------- GEMM: C[M,N] = A[M,K] @ B[N,K]^T + bias ----------------
// m97 structure: 128x128 tile, BK=32, 4 waves (2x2), global_load_lds staging.
// EPI: 0 = bias, store bf16 ; 1 = bias, store fp32 ; 2 = bias+erf-GELU, store bf16
template <int EPI>
__global__ __launch_bounds__(256) void gemm_bt(const u16* __restrict__ A,
                                               const u16* __restrict__ Bw,
                                               const float* __restrict__ bias,
                                               float* __restrict__ Cf,
                                               u16* __restrict__ Cb,
                                               int N, int K) {
    __shared__ u16 sA[128 * 32];
    __shared__ u16 sB[128 * 32];
    const int tid = threadIdx.x;
    const int wid = tid >> 6, lane = tid & 63;
    const int lrow = lane & 15, lgrp = lane >> 4;

    // bijective XCD swizzle (m204)
    const int nbx = gridDim.x;
    const int nwg = nbx * gridDim.y;
    const int orig = blockIdx.y * nbx + blockIdx.x;
    const int qd = nwg >> 3, rr = nwg & 7, xc = orig & 7, oi = orig >> 3;
    const int swz = (xc < rr ? xc * (qd + 1) : rr * (qd + 1) + (xc - rr) * qd) + oi;
    const int m0 = (swz % nbx) * 128, n0 = (swz / nbx) * 128;

    const int wm = wid >> 1, wn = wid & 1;
    const int ar = lane >> 2, ac = lane & 3;

    floatx4 acc[4][4] = {};
    const u16* Ab = A + (size_t)m0 * K;
    const u16* Bb = Bw + (size_t)n0 * K;

    for (int k0 = 0; k0 < K; k0 += 32) {
#pragma unroll
        for (int i = 0; i < 2; i++) {
            int seg = wid * 2 + i;
            int row = seg * 16 + ar;
            g2l16(Ab + (size_t)row * K + k0 + ac * 8, &sA[seg * 512]);
            g2l16(Bb + (size_t)row * K + k0 + ac * 8, &sB[seg * 512]);
        }
        __syncthreads();
        short8 af[4], bfr[4];
#pragma unroll
        for (int mi = 0; mi < 4; mi++)
            af[mi] = *reinterpret_cast<const short8*>(
                &sA[(wm * 64 + mi * 16 + lrow) * 32 + lgrp * 8]);
#pragma unroll
        for (int ni = 0; ni < 4; ni++)
            bfr[ni] = *reinterpret_cast<const short8*>(
                &sB[(wn * 64 + ni * 16 + lrow) * 32 + lgrp * 8]);
#pragma unroll
        for (int mi = 0; mi < 4; mi++)
#pragma unroll
            for (int ni = 0; ni < 4; ni++)
                acc[mi][ni] = __builtin_amdgcn_mfma_f32_16x16x32_bf16(
                    af[mi], bfr[ni], acc[mi][ni], 0, 0, 0);
        __syncthreads();
    }

#pragma unroll
    for (int mi = 0; mi < 4; mi++) {
        int row = m0 + wm * 64 + mi * 16 + lgrp * 4;
#pragma unroll
        for (int ni = 0; ni < 4; ni++) {
            int col = n0 + wn * 64 + ni * 16 + lrow;
            float bc = bias[col];
#pragma unroll
            for (int j = 0; j < 4; j++) {
                float v = acc[mi][ni][j] + bc;
                if (EPI == 2) v = 0.5f * v * (1.0f + erff(v * 0.70710678118654752f));
                if (EPI == 1)
                    Cf[(size_t)(row + j) * N + col] = v;
                else
                    Cb[(size_t)(row + j) * N + col] = f2bf(v);
            }
        }
    }
}

// ---------------- flash attention v3 (swapped QK^T, lane-local softmax) -----
// QKV packed [M][3072] bf16. Block = (b,h) x 64 q-rows; 4 waves x 16 rows.
// S^T = mfma(K,Q): lane owns q-column (q=lane&15), 16 kv scores in regs.
// Reduce = 15 in-reg ops + 2 shfl_xor. mask as additive mbias, fused in FMA.
// Defer-max (THR=8). P stored [q][kv] XOR-swizzled, read as plain A-frags.
__global__ __launch_bounds__(256) void attn_kernel(const u16* __restrict__ QKV,
                                                   const float* __restrict__ mbias,
                                                   u16* __restrict__ O) {
    const int SD = 3 * D_;
    __shared__ alignas(16) u16 ktL[2][4096];   // [buf][64 kv][64 d] src-swizzled
    __shared__ alignas(16) u16 vtL[2][4096];   // [buf] tr-subtiled V
    __shared__ alignas(16) u16 pL[4][1024];    // per-wave P [16 q][64 kv] swizzled

    const int orig = blockIdx.y * gridDim.x + blockIdx.x;   // 1024 wgs
    const int swz = (orig & 7) * 128 + (orig >> 3);
    const int qt = swz & 31, bh = swz >> 5;
    const int b = bh >> 4, h = bh & 15;

    const int tid = threadIdx.x, wid = tid >> 6, lane = tid & 63;
    const int lrow = lane & 15, lgrp = lane >> 4;

    const u16* Qp = QKV + h * DK_;
    const u16* Kp = QKV + D_ + h * DK_;
    const u16* Vp = QKV + 2 * D_ + h * DK_;
    const float* mbrow = mbias + b * S_;

    // Q fragments (B-operand of swapped QK^T): col=q=lrow, k=d
    const int qr = qt * 64 + wid * 16 + lrow;
    const u16* qrow = Qp + (size_t)(b * S_ + qr) * SD;
    short8 aq0 = *reinterpret_cast<const short8*>(qrow + lgrp * 8);
    short8 aq1 = *reinterpret_cast<const short8*>(qrow + 32 + lgrp * 8);

    // staging source pointers (same as verified r2)
    const u16* kq[2];
    const u16* vq[2];
#pragma unroll
    for (int i = 0; i < 2; i++) {
        int s = wid * 2 + i;
        int q8 = s * 64 + lane;
        int krow = q8 >> 3, kcb = q8 & 7;
        kq[i] = Kp + (size_t)(b * S_ + krow) * SD + ((kcb ^ (krow & 7)) * 8);
        int o = s * 512 + lane * 8;
        int vk = ((o >> 6) & 7) * 8 + ((o >> 9) & 1) * 4 + ((o >> 4) & 3);
        int vd = (o >> 10) * 16 + (o & 8);
        vq[i] = Vp + (size_t)(b * S_ + vk) * SD + vd;
    }

    auto issue = [&](int bufIdx) {
        u16* kb_ = ktL[bufIdx];
        u16* vb_ = vtL[bufIdx];
#pragma unroll
        for (int i = 0; i < 2; i++) {
            int s = wid * 2 + i;
            g2l16(kq[i], kb_ + s * 512);
            g2l16(vq[i], vb_ + s * 512);
            kq[i] += 64 * SD;
            vq[i] += 64 * SD;
        }
    };

    floatx4 accO[4] = {};
    float mrun = -1e30f, lrun = 0.f;

    issue(0);
    int cur = 0;
    for (int t = 0; t < S_ / 64; t++) {
        const int kv0 = t * 64;
        if (t < S_ / 64 - 1) {
            issue(cur ^ 1);
            asm volatile("s_waitcnt vmcnt(4)" ::: "memory");
        } else {
            asm volatile("s_waitcnt vmcnt(0)" ::: "memory");
        }
        __builtin_amdgcn_s_barrier();
        asm volatile("" ::: "memory");

        const u16* ktc = ktL[cur];
        const unsigned vva = lds_off(vtL[cur]) + lane * 8;

        // mbias: 4 x float4, kv = ni*16 + lgrp*4 .. +3 (aligned)
        float4 mb[4];
#pragma unroll
        for (int ni = 0; ni < 4; ni++)
            mb[ni] = *reinterpret_cast<const float4*>(mbrow + kv0 + ni * 16 + lgrp * 4);

        // ---- swapped QK^T: S^T[kv][q] ----
        floatx4 st[4];
        __builtin_amdgcn_s_setprio(1);
#pragma unroll
        for (int ni = 0; ni < 4; ni++) {
            int row = ni * 16 + lrow;
            int off0 = (row * 128 + lgrp * 16) ^ ((lrow & 7) << 4);
            int off1 = (row * 128 + 64 + lgrp * 16) ^ ((lrow & 7) << 4);
            short8 bk0 = *reinterpret_cast<const short8*>((const char*)ktc + off0);
            short8 bk1 = *reinterpret_cast<const short8*>((const char*)ktc + off1);
            floatx4 z = {0.f, 0.f, 0.f, 0.f};
            z = __builtin_amdgcn_mfma_f32_16x16x32_bf16(bk0, aq0, z, 0, 0, 0);
            z = __builtin_amdgcn_mfma_f32_16x16x32_bf16(bk1, aq1, z, 0, 0, 0);
            st[ni] = z;   // st[ni][j]: kv = ni*16 + lgrp*4 + j, q = lrow
        }
        __builtin_amdgcn_s_setprio(0);

        // scores = z*0.125 + mbias ; lane-local max over its 16 kv
        float pm[4][4];
#pragma unroll
        for (int ni = 0; ni < 4; ni++) {
            const float* mbp = reinterpret_cast<const float*>(&mb[ni]);
#pragma unroll
            for (int j = 0; j < 4; j++)
                pm[ni][j] = fmaf(st[ni][j], 0.125f, mbp[j]);
        }
        float pmax = pm[0][0];
#pragma unroll
        for (int ni = 0; ni < 4; ni++)
#pragma unroll
            for (int j = 0; j < 4; j++) pmax = fmaxf(pmax, pm[ni][j]);
        pmax = fmaxf(pmax, __shfl_xor(pmax, 16, 64));
        pmax = fmaxf(pmax, __shfl_xor(pmax, 32, 64));

        // defer-max (T13, THR=8)
        bool upd = !__all(pmax - mrun <= 8.0f);
        float fac = 1.0f;
        if (upd) {
            float mn = fmaxf(mrun, pmax);
            fac = __expf(mrun - mn);
            mrun = mn;
        }

        // exp + lane-local sum
        float p[4][4];
        float s = 0.f;
#pragma unroll
        for (int ni = 0; ni < 4; ni++)
#pragma unroll
            for (int j = 0; j < 4; j++) {
                float e = __expf(pm[ni][j] - mrun);
                p[ni][j] = e;
                s += e;
            }
        s += __shfl_xor(s, 16, 64);
        s += __shfl_xor(s, 32, 64);
        lrun = lrun * fac + s;

        // ---- P -> LDS [q=lrow][kv] XOR-swizzled (kv-contiguous bf16x4) ----
#pragma unroll
        for (int ni = 0; ni < 4; ni++) {
            bf16x4 pw;
#pragma unroll
            for (int j = 0; j < 4; j++) pw[j] = (short)f2bf_fast(p[ni][j]);
            unsigned woff = (unsigned)((lrow * 128 + ni * 32 + lgrp * 8) ^ ((lrow & 7) << 4));
            *reinterpret_cast<bf16x4*>((char*)pL[wid] + woff) = pw;
        }

        // rescale accO while P writes land (rare with defer-max)
        if (upd) {
            float f0 = __shfl(fac, lgrp * 4 + 0, 64);
            float f1 = __shfl(fac, lgrp * 4 + 1, 64);
            float f2 = __shfl(fac, lgrp * 4 + 2, 64);
            float f3 = __shfl(fac, lgrp * 4 + 3, 64);
#pragma unroll
            for (int nd = 0; nd < 4; nd++) {
                floatx4 tt = accO[nd];
                tt[0] *= f0; tt[1] *= f1; tt[2] *= f2; tt[3] *= f3;
                accO[nd] = tt;
            }
        }

        asm volatile("s_waitcnt lgkmcnt(0)" ::: "memory");
        __builtin_amdgcn_sched_barrier(0);

        // P A-frags: row=q=lrow, k=kv
        unsigned ra0 = (unsigned)((lrow * 128 + lgrp * 16) ^ ((lrow & 7) << 4));
        unsigned ra1 = (unsigned)((lrow * 128 + 64 + lgrp * 16) ^ ((lrow & 7) << 4));
        short8 ap0 = *reinterpret_cast<const short8*>((const char*)pL[wid] + ra0);
        short8 ap1 = *reinterpret_cast<const short8*>((const char*)pL[wid] + ra1);

        // V fragments via hardware transpose read
        short8 bv0[4], bv1[4];
#pragma unroll
        for (int nd = 0; nd < 4; nd++) {
            unsigned a = vva + nd * 2048;
            bf16x4 t0, t1, t2, t3;
            TRB16(t0, a, 0);
            TRB16(t1, a, 1024);
            TRB16(t2, a, 512);
            TRB16(t3, a, 1536);
            bv0[nd] = __builtin_shufflevector(t0, t1, 0, 1, 2, 3, 4, 5, 6, 7);
            bv1[nd] = __builtin_shufflevector(t2, t3, 0, 1, 2, 3, 4, 5, 6, 7);
        }
        asm volatile("s_waitcnt lgkmcnt(0)" ::: "memory");
        __builtin_amdgcn_sched_barrier(0);

        __builtin_amdgcn_s_setprio(1);
#pragma unroll
        for (int nd = 0; nd < 4; nd++) {
            accO[nd] = __builtin_amdgcn_mfma_f32_16x16x32_bf16(ap0, bv0[nd], accO[nd], 0, 0, 0);
            accO[nd] = __builtin_amdgcn_mfma_f32_16x16x32_bf16(ap1, bv1[nd], accO[nd], 0, 0, 0);
        }
        __builtin_amdgcn_s_setprio(0);

        asm volatile("" ::: "memory");
        __builtin_amdgcn_s_barrier();
        cur ^= 1;
    }

    // epilogue: O = accO / l  (l owned by lane of that q-column)
    float linv = 1.0f / lrun;
    float li[4];
#pragma unroll
    for (int j = 0; j < 4; j++) li[j] = __shfl(linv, lgrp * 4 + j, 64);
#pragma unroll
    for (int nd = 0; nd < 4; nd++)
#pragma unroll
        for (int j = 0; j < 4; j++) {
            int r = lgrp * 4 + j;
            float v = accO[nd][j] * li[j];
            O[(size_t)(b * S_ + qt * 64 + wid * 16 + r) * D_ + h * DK_ + nd * 16 + lrow] =
                f2bf_fast(v);
        }
}

// ---------------- residual + LayerNorm (torch: ddof=1, eps outside sqrt) ----
__global__ __launch_bounds__(256) void ln_kernel(const float* __restrict__ X,
                                                 const float* __restrict__ R,
                                                 const float* __restrict__ gam,
                                                 const float* __restrict__ bet,
                                                 float* __restrict__ outf,
                                                 u16* __restrict__ outb) {
    __shared__ float ws1[4], ws2[4];
    const int row = blockIdx.x, tid = threadIdx.x;
    const float4 x = reinterpret_cast<const float4*>(X + (size_t)row * D_)[tid];
    const float4 r = reinterpret_cast<const float4*>(R + (size_t)row * D_)[tid];
    float4 v; v.x = x.x + r.x; v.y = x.y + r.y; v.z = x.z + r.z; v.w = x.w + r.w;

    float s = v.x + v.y + v.z + v.w;
#pragma unroll
    for (int m = 32; m >= 1; m >>= 1) s += __shfl_xor(s, m, 64);
    if ((tid & 63) == 0) ws1[tid >> 6] = s;
    __syncthreads();
    float mean = (ws1[0] + ws1[1] + ws1[2] + ws1[3]) * (1.f / D_);

    float4 d; d.x = v.x - mean; d.y = v.y - mean; d.z = v.z - mean; d.w = v.w - mean;
    float q = d.x * d.x + d.y * d.y + d.z * d.z + d.w * d.w;
#pragma unroll
    for (int m = 32; m >= 1; m >>= 1) q += __shfl_xor(q, m, 64);
    if ((tid & 63) == 0) ws2[tid >> 6] = q;
    __syncthreads();
    float var = (ws2[0] + ws2[1] + ws2[2] + ws2[3]) * (1.f / (D_ - 1));
    float inv = 1.f / (sqrtf(var) + 1e-6f);

    const float4 g = reinterpret_cast<const float4*>(gam)[tid];
    const float4 bb = reinterpret_cast<const float4*>(bet)[tid];
    float4 o;
    o.x = g.x * d.x * inv + bb.x;
    o.y = g.y * d.y * inv + bb.y;
    o.z = g.z * d.z * inv + bb.z;
    o.w = g.w * d.w * inv + bb.w;
    if (outf) reinterpret_cast<float4*>(outf + (size_t)row * D_)[tid] = o;
    if (outb) {
        ushort4 ob;
        ob.x = f2bf(o.x); ob.y = f2bf(o.y); ob.z = f2bf(o.z); ob.w = f2bf(o.w);
        reinterpret_cast<ushort4*>(outb + (size_t)row * D_)[tid] = ob;
    }
}

// ---------------- launcher ----------------
extern "C" void kernel_launch(void* const* d_in, const int* in_sizes, int n_in,
                              void* d_out, int out_size, void* d_ws, size_t ws_size,
                              hipStream_t stream) {
    const float* x    = (const float*)d_in[0];
    const int*   mask = (const int*)d_in[1];
    const float* wq   = (const float*)d_in[2];
    const float* bq   = (const float*)d_in[3];
    const float* wk   = (const float*)d_in[4];
    const float* bk   = (const float*)d_in[5];
    const float* wv   = (const float*)d_in[6];
    const float* bv   = (const float*)d_in[7];
    const float* wo   = (const float*)d_in[8];
    const float* bo   = (const float*)d_in[9];
    const float* g1   = (const float*)d_in[10];
    const float* b1   = (const float*)d_in[11];
    const float* g2   = (const float*)d_in[12];
    const float* b2   = (const float*)d_in[13];
    const float* w1   = (const float*)d_in[14];
    const float* bf1  = (const float*)d_in[15];
    const float* w2   = (const float*)d_in[16];
    const float* bf2  = (const float*)d_in[17];
    float* out = (float*)d_out;

    char* ws = (char*)d_ws;
    size_t off = 0;
    auto alloc = [&](size_t bytes) -> void* {
        void* p = ws + off;
        off += (bytes + 255) & ~(size_t)255;
        return p;
    };
    u16*   xb    = (u16*)  alloc((size_t)M_ * D_ * 2);
    u16*   wqkvb = (u16*)  alloc((size_t)3 * D_ * D_ * 2);
    u16*   wob   = (u16*)  alloc((size_t)D_ * D_ * 2);
    u16*   w1b   = (u16*)  alloc((size_t)DFF_ * D_ * 2);
    u16*   w2b   = (u16*)  alloc((size_t)D_ * DFF_ * 2);
    float* bqkv  = (float*)alloc((size_t)3 * D_ * 4);
    float* mbias = (float*)alloc((size_t)B_ * S_ * 4);
    u16*   qkvb  = (u16*)  alloc((size_t)M_ * 3 * D_ * 2);
    u16*   cvb   = (u16*)  alloc((size_t)M_ * D_ * 2);
    float* projf = (float*)alloc((size_t)M_ * D_ * 4);
    float* hdf   = (float*)alloc((size_t)M_ * D_ * 4);
    u16*   hdb   = (u16*)  alloc((size_t)M_ * D_ * 2);
    u16*   ff1b  = (u16*)  alloc((size_t)M_ * DFF_ * 2);
    float* ff2f  = (float*)alloc((size_t)M_ * D_ * 4);

    // fused conversions + misc prep (2 launches instead of 8)
    cvt_all<<<2048, 256, 0, stream>>>(x, wq, wk, wv, wo, w1, w2,
                                      xb, wqkvb, wob, w1b, w2b);
    prep_misc<<<28, 256, 0, stream>>>(bq, bk, bv, mask, bqkv, mbias);

    // fused QKV projection: [4096,3072,1024]
    gemm_bt<0><<<dim3(M_ / 128, 3 * D_ / 128), 256, 0, stream>>>(
        xb, wqkvb, bqkv, nullptr, qkvb, 3 * D_, D_);

    // attention
    attn_kernel<<<dim3(S_ / 64, B_ * H_), 256, 0, stream>>>(qkvb, mbias, cvb);

    // output projection: [4096,1024,1024] -> fp32
    gemm_bt<1><<<dim3(M_ / 128, D_ / 128), 256, 0, stream>>>(
        cvb, wob, bo, projf, nullptr, D_, D_);

    // residual + LN1 -> hdf (fp32), hdb (bf16)
    ln_kernel<<<M_, 256, 0, stream>>>(x, projf, g1, b1, hdf, hdb);

    // FFN1 + GELU: [4096,4096,1024] -> bf16
    gemm_bt<2><<<dim3(M_ / 128, DFF_ / 128), 256, 0, stream>>>(
        hdb, w1b, bf1, nullptr, ff1b, DFF_, D_);

    // FFN2: [4096,1024,4096] -> fp32
    gemm_bt<1><<<dim3(M_ / 128, D_ / 128), 256, 0, stream>>>(
        ff1b, w2b, bf2, ff2f, nullptr, D_, DFF_);

    // residual + LN2 -> out (fp32)
    ln_kernel<<<M_, 256, 0, stream>>>(hdf, ff2f, g2, b2, out, nullptr);
}

// Round 4
// 455.680 us; speedup vs baseline: 1.2323x; 1.0542x over previous
//
#include <hip/hip_runtime.h>
#include <hip/hip_bf16.h>

// ---------------- constants (problem shape) ----------------
#define B_   2
#define S_   2048
#define D_   1024
#define H_   16
#define DK_  64
#define DFF_ 4096
#define M_   (B_*S_)   // 4096 rows

typedef unsigned short u16;
typedef __attribute__((ext_vector_type(8))) short short8;
typedef __attribute__((ext_vector_type(4))) short bf16x4;
typedef __attribute__((ext_vector_type(4))) float floatx4;

// fp32 -> bf16 round-to-nearest-even (manual, used in GEMM epilogue)
__device__ __forceinline__ u16 f2bf(float f) {
    union { float f; unsigned u; } v; v.f = f;
    unsigned r = v.u + 0x7fffu + ((v.u >> 16) & 1u);
    return (u16)(r >> 16);
}
// compiler path (emits v_cvt_pk_bf16_f32 for pairs)
__device__ __forceinline__ u16 f2bf_fast(float f) {
    __hip_bfloat16 h = __float2bfloat16(f);
    return *reinterpret_cast<u16*>(&h);
}

// async global->LDS, 16B per lane. LDS dest must be wave-uniform base.
__device__ __forceinline__ void g2l16(const u16* g, u16* l) {
    __builtin_amdgcn_global_load_lds((const __attribute__((address_space(1))) void*)g,
                                     (__attribute__((address_space(3))) void*)l,
                                     16, 0, 0);
}

__device__ __forceinline__ unsigned lds_off(const void* p) {
    return (unsigned)(unsigned long long)p;
}

#define TRB16(dst, va, IMM)                                                    \
    asm volatile("ds_read_b64_tr_b16 %0, %1 offset:" #IMM                      \
                 : "=v"(dst) : "v"(va))

// ---------------- fused fp32->bf16 conversion of x + all weights ----------------
__global__ __launch_bounds__(256) void cvt_all(
    const float* __restrict__ x,  const float* __restrict__ wq,
    const float* __restrict__ wk, const float* __restrict__ wv,
    const float* __restrict__ wo, const float* __restrict__ w1,
    const float* __restrict__ w2,
    u16* __restrict__ xb, u16* __restrict__ wqkvb, u16* __restrict__ wob,
    u16* __restrict__ w1b, u16* __restrict__ w2b) {
    for (int i = blockIdx.x * 256 + threadIdx.x; i < 4194304;
         i += gridDim.x * 256) {
        const float* s; u16* d; int off;
        if (i < 1048576)      { s = x;  d = xb;    off = i; }
        else if (i < 1310720) { s = wq; d = wqkvb; off = i - 1048576; }
        else if (i < 1572864) { s = wk; d = wqkvb + 1048576; off = i - 1310720; }
        else if (i < 1835008) { s = wv; d = wqkvb + 2097152; off = i - 1572864; }
        else if (i < 2097152) { s = wo; d = wob;   off = i - 1835008; }
        else if (i < 3145728) { s = w1; d = w1b;   off = i - 2097152; }
        else                  { s = w2; d = w2b;   off = i - 3145728; }
        float4 v = reinterpret_cast<const float4*>(s)[off];
        ushort4 o;
        o.x = f2bf(v.x); o.y = f2bf(v.y); o.z = f2bf(v.z); o.w = f2bf(v.w);
        reinterpret_cast<ushort4*>(d)[off] = o;
    }
}

// bias concat (3072) + mask->mbias (4096). grid 28x256
__global__ __launch_bounds__(256) void prep_misc(const float* __restrict__ bq,
                                                 const float* __restrict__ bk,
                                                 const float* __restrict__ bv,
                                                 const int* __restrict__ mask,
                                                 float* __restrict__ bqkv,
                                                 float* __restrict__ mbias) {
    int i = blockIdx.x * 256 + threadIdx.x;
    if (i < 3 * D_) {
        float v = (i < D_) ? bq[i] : (i < 2 * D_) ? bk[i - D_] : bv[i - 2 * D_];
        bqkv[i] = v;
    } else if (i < 3 * D_ + B_ * S_) {
        int k = i - 3 * D_;
        mbias[k] = (mask[k] == 0) ? -1e9f : 0.0f;
    }
}

// ---------------- 256x256 8-phase GEMM: C[M,N] = A[M,K] @ B[N,K]^T + bias ----
// BM=BN=256, BK=64, 8 waves (2Mx4N), 512 thr, LDS 128KiB (2 parities).
// Per phase: ds_read frag subtile + stage one 16KB half-tile + barrier +
// lgkmcnt(0) + 16 MFMA + barrier. Counted vmcnt(4) only at phase 4.
// Race-free stagger: A-halves(t+1) staged ph0/1 (other parity, dead since t-1);
// B-halves(t+2) staged ph2/3 (B[par] dies after ph0).
// LDS XOR swizzle (attn-K-verified pattern): read chunk g -> g ^ (row&7),
// staged via pre-swizzled global source (linear DMA dest).
// EPI: 0 = bias, store bf16 ; 2 = bias + erf-GELU, store bf16
template <int EPI>
__global__ __launch_bounds__(512, 2) void gemm256_bt(const u16* __restrict__ A,
                                                     const u16* __restrict__ Bw,
                                                     const float* __restrict__ bias,
                                                     u16* __restrict__ Cb,
                                                     int N, int K) {
    __shared__ alignas(16) u16 sA[2][2][8192];   // [parity][half][128 rows x 64 k]
    __shared__ alignas(16) u16 sB[2][2][8192];
    const int tid = threadIdx.x;
    const int wid = tid >> 6, lane = tid & 63;
    const int lrow = lane & 15, lgrp = lane >> 4;
    const int wm = wid >> 2, wn = wid & 3;       // 2 x 4 wave grid

    // bijective XCD swizzle (m204)
    const int nbx = gridDim.x;
    const int nwg = nbx * gridDim.y;
    const int orig = blockIdx.y * nbx + blockIdx.x;
    const int qd = nwg >> 3, rr = nwg & 7, xc = orig & 7, oi = orig >> 3;
    const int swz = (xc < rr ? xc * (qd + 1) : rr * (qd + 1) + (xc - rr) * qd) + oi;
    const int m0 = (swz % nbx) * 256, n0 = (swz / nbx) * 256;

    const u16* Ab = A + (size_t)m0 * K;
    const u16* Bb = Bw + (size_t)n0 * K;
    const int T = K >> 6;

    // staging: chunk c = (wid*2+i)*64 + lane; dest u16 = c*8 (linear);
    // source holds data for read-chunk (c&7) ^ (row&7)
    const int c0 = (wid * 2 + 0) * 64 + lane;
    const int c1 = (wid * 2 + 1) * 64 + lane;
    const int r0 = c0 >> 3, g0 = c0 & 7;
    const int r1 = c1 >> 3, g1 = c1 & 7;
    const size_t so0 = (size_t)r0 * K + (size_t)((g0 ^ (r0 & 7)) * 8);
    const size_t so1 = (size_t)r1 * K + (size_t)((g1 ^ (r1 & 7)) * 8);
    const int d0 = (wid * 2 + 0) * 512;
    const int d1 = (wid * 2 + 1) * 512;

    auto stageA = [&](int par, int half, int kt) {
        const u16* src = Ab + (size_t)(half * 128) * K + kt * 64;
        g2l16(src + so0, &sA[par][half][d0]);
        g2l16(src + so1, &sA[par][half][d1]);
    };
    auto stageB = [&](int par, int half, int kt) {
        const u16* src = Bb + (size_t)(half * 128) * K + kt * 64;
        g2l16(src + so0, &sB[par][half][d0]);
        g2l16(src + so1, &sB[par][half][d1]);
    };

    // prologue: K-tile 0 fully + B of K-tile 1 (oldest 8 loads = K0)
    stageA(0, 0, 0); stageA(0, 1, 0);
    stageB(0, 0, 0); stageB(0, 1, 0);
    if (T > 1) { stageB(1, 0, 1); stageB(1, 1, 1); }
    asm volatile("s_waitcnt vmcnt(4)" ::: "memory");
    asm volatile("s_barrier" ::: "memory");

    floatx4 acc[8][4] = {};
    const int rbase = (wn & 1) * 64;             // B row base within half
    const int bhalf = wn >> 1;

    for (int t = 0; t < T; t++) {
        const int par = t & 1;
        const char* baseA = (const char*)&sA[par][wm][0];
        const char* baseB = (const char*)&sB[par][bhalf][0];
        short8 bfr[4][2];
#pragma unroll
        for (int ph = 0; ph < 4; ph++) {
            // ---- ds_read frag subtile ----
            if (ph == 0) {
#pragma unroll
                for (int nj = 0; nj < 4; nj++) {
                    int rb = rbase + nj * 16 + lrow;
#pragma unroll
                    for (int kk = 0; kk < 2; kk++) {
                        int off = rb * 128 + (((kk * 4 + lgrp) ^ (lrow & 7)) * 16);
                        bfr[nj][kk] = *reinterpret_cast<const short8*>(baseB + off);
                    }
                }
            }
            short8 af[2][2];
#pragma unroll
            for (int a = 0; a < 2; a++) {
                int ra = (2 * ph + a) * 16 + lrow;
#pragma unroll
                for (int kk = 0; kk < 2; kk++) {
                    int off = ra * 128 + (((kk * 4 + lgrp) ^ (lrow & 7)) * 16);
                    af[a][kk] = *reinterpret_cast<const short8*>(baseA + off);
                }
            }
            // ---- stage one half-tile ----
            if (ph == 0) { if (t + 1 < T) stageA(par ^ 1, 0, t + 1); }
            if (ph == 1) { if (t + 1 < T) stageA(par ^ 1, 1, t + 1); }
            if (ph == 2) { if (t + 2 < T) stageB(par, 0, t + 2); }
            if (ph == 3) { if (t + 2 < T) stageB(par, 1, t + 2); }

            asm volatile("s_barrier" ::: "memory");
            asm volatile("s_waitcnt lgkmcnt(0)" ::: "memory");
            __builtin_amdgcn_sched_barrier(0);

            __builtin_amdgcn_s_setprio(1);
#pragma unroll
            for (int a = 0; a < 2; a++)
#pragma unroll
                for (int nj = 0; nj < 4; nj++) {
                    acc[2 * ph + a][nj] = __builtin_amdgcn_mfma_f32_16x16x32_bf16(
                        af[a][0], bfr[nj][0], acc[2 * ph + a][nj], 0, 0, 0);
                    acc[2 * ph + a][nj] = __builtin_amdgcn_mfma_f32_16x16x32_bf16(
                        af[a][1], bfr[nj][1], acc[2 * ph + a][nj], 0, 0, 0);
                }
            __builtin_amdgcn_s_setprio(0);

            if (ph == 3) {
                if (t >= T - 3) asm volatile("s_waitcnt vmcnt(0)" ::: "memory");
                else            asm volatile("s_waitcnt vmcnt(4)" ::: "memory");
            }
            asm volatile("s_barrier" ::: "memory");
        }
    }

    // epilogue
#pragma unroll
    for (int mi = 0; mi < 8; mi++) {
        int row = m0 + wm * 128 + mi * 16 + lgrp * 4;
#pragma unroll
        for (int nj = 0; nj < 4; nj++) {
            int col = n0 + wn * 64 + nj * 16 + lrow;
            float bc = bias[col];
#pragma unroll
            for (int j = 0; j < 4; j++) {
                float v = acc[mi][nj][j] + bc;
                if (EPI == 2) v = 0.5f * v * (1.0f + erff(v * 0.70710678118654752f));
                Cb[(size_t)(row + j) * N + col] = f2bf(v);
            }
        }
    }
}

// ---------------- 128x128 GEMM (m97 structure) for small-N shapes ----------
// EPI: 1 = bias, store fp32
template <int EPI>
__global__ __launch_bounds__(256) void gemm_bt(const u16* __restrict__ A,
                                               const u16* __restrict__ Bw,
                                               const float* __restrict__ bias,
                                               float* __restrict__ Cf,
                                               u16* __restrict__ Cb,
                                               int N, int K) {
    __shared__ u16 sA[128 * 32];
    __shared__ u16 sB[128 * 32];
    const int tid = threadIdx.x;
    const int wid = tid >> 6, lane = tid & 63;
    const int lrow = lane & 15, lgrp = lane >> 4;

    const int nbx = gridDim.x;
    const int nwg = nbx * gridDim.y;
    const int orig = blockIdx.y * nbx + blockIdx.x;
    const int qd = nwg >> 3, rr = nwg & 7, xc = orig & 7, oi = orig >> 3;
    const int swz = (xc < rr ? xc * (qd + 1) : rr * (qd + 1) + (xc - rr) * qd) + oi;
    const int m0 = (swz % nbx) * 128, n0 = (swz / nbx) * 128;

    const int wm = wid >> 1, wn = wid & 1;
    const int ar = lane >> 2, ac = lane & 3;

    floatx4 acc[4][4] = {};
    const u16* Ab = A + (size_t)m0 * K;
    const u16* Bb = Bw + (size_t)n0 * K;

    for (int k0 = 0; k0 < K; k0 += 32) {
#pragma unroll
        for (int i = 0; i < 2; i++) {
            int seg = wid * 2 + i;
            int row = seg * 16 + ar;
            g2l16(Ab + (size_t)row * K + k0 + ac * 8, &sA[seg * 512]);
            g2l16(Bb + (size_t)row * K + k0 + ac * 8, &sB[seg * 512]);
        }
        __syncthreads();
        short8 af[4], bfr[4];
#pragma unroll
        for (int mi = 0; mi < 4; mi++)
            af[mi] = *reinterpret_cast<const short8*>(
                &sA[(wm * 64 + mi * 16 + lrow) * 32 + lgrp * 8]);
#pragma unroll
        for (int ni = 0; ni < 4; ni++)
            bfr[ni] = *reinterpret_cast<const short8*>(
                &sB[(wn * 64 + ni * 16 + lrow) * 32 + lgrp * 8]);
#pragma unroll
        for (int mi = 0; mi < 4; mi++)
#pragma unroll
            for (int ni = 0; ni < 4; ni++)
                acc[mi][ni] = __builtin_amdgcn_mfma_f32_16x16x32_bf16(
                    af[mi], bfr[ni], acc[mi][ni], 0, 0, 0);
        __syncthreads();
    }

#pragma unroll
    for (int mi = 0; mi < 4; mi++) {
        int row = m0 + wm * 64 + mi * 16 + lgrp * 4;
#pragma unroll
        for (int ni = 0; ni < 4; ni++) {
            int col = n0 + wn * 64 + ni * 16 + lrow;
            float bc = bias[col];
#pragma unroll
            for (int j = 0; j < 4; j++) {
                float v = acc[mi][ni][j] + bc;
                if (EPI == 1)
                    Cf[(size_t)(row + j) * N + col] = v;
                else
                    Cb[(size_t)(row + j) * N + col] = f2bf(v);
            }
        }
    }
}

// ---------------- flash attention (swapped QK^T, lane-local softmax) --------
__global__ __launch_bounds__(256) void attn_kernel(const u16* __restrict__ QKV,
                                                   const float* __restrict__ mbias,
                                                   u16* __restrict__ O) {
    const int SD = 3 * D_;
    __shared__ alignas(16) u16 ktL[2][4096];
    __shared__ alignas(16) u16 vtL[2][4096];
    __shared__ alignas(16) u16 pL[4][1024];

    const int orig = blockIdx.y * gridDim.x + blockIdx.x;   // 1024 wgs
    const int swz = (orig & 7) * 128 + (orig >> 3);
    const int qt = swz & 31, bh = swz >> 5;
    const int b = bh >> 4, h = bh & 15;

    const int tid = threadIdx.x, wid = tid >> 6, lane = tid & 63;
    const int lrow = lane & 15, lgrp = lane >> 4;

    const u16* Qp = QKV + h * DK_;
    const u16* Kp = QKV + D_ + h * DK_;
    const u16* Vp = QKV + 2 * D_ + h * DK_;
    const float* mbrow = mbias + b * S_;

    const int qr = qt * 64 + wid * 16 + lrow;
    const u16* qrow = Qp + (size_t)(b * S_ + qr) * SD;
    short8 aq0 = *reinterpret_cast<const short8*>(qrow + lgrp * 8);
    short8 aq1 = *reinterpret_cast<const short8*>(qrow + 32 + lgrp * 8);

    const u16* kq[2];
    const u16* vq[2];
#pragma unroll
    for (int i = 0; i < 2; i++) {
        int s = wid * 2 + i;
        int q8 = s * 64 + lane;
        int krow = q8 >> 3, kcb = q8 & 7;
        kq[i] = Kp + (size_t)(b * S_ + krow) * SD + ((kcb ^ (krow & 7)) * 8);
        int o = s * 512 + lane * 8;
        int vk = ((o >> 6) & 7) * 8 + ((o >> 9) & 1) * 4 + ((o >> 4) & 3);
        int vd = (o >> 10) * 16 + (o & 8);
        vq[i] = Vp + (size_t)(b * S_ + vk) * SD + vd;
    }

    auto issue = [&](int bufIdx) {
        u16* kb_ = ktL[bufIdx];
        u16* vb_ = vtL[bufIdx];
#pragma unroll
        for (int i = 0; i < 2; i++) {
            int s = wid * 2 + i;
            g2l16(kq[i], kb_ + s * 512);
            g2l16(vq[i], vb_ + s * 512);
            kq[i] += 64 * SD;
            vq[i] += 64 * SD;
        }
    };

    floatx4 accO[4] = {};
    float mrun = -1e30f, lrun = 0.f;

    issue(0);
    int cur = 0;
    for (int t = 0; t < S_ / 64; t++) {
        const int kv0 = t * 64;
        if (t < S_ / 64 - 1) {
            issue(cur ^ 1);
            asm volatile("s_waitcnt vmcnt(4)" ::: "memory");
        } else {
            asm volatile("s_waitcnt vmcnt(0)" ::: "memory");
        }
        __builtin_amdgcn_s_barrier();
        asm volatile("" ::: "memory");

        const u16* ktc = ktL[cur];
        const unsigned vva = lds_off(vtL[cur]) + lane * 8;

        float4 mb[4];
#pragma unroll
        for (int ni = 0; ni < 4; ni++)
            mb[ni] = *reinterpret_cast<const float4*>(mbrow + kv0 + ni * 16 + lgrp * 4);

        floatx4 st[4];
        __builtin_amdgcn_s_setprio(1);
#pragma unroll
        for (int ni = 0; ni < 4; ni++) {
            int row = ni * 16 + lrow;
            int off0 = (row * 128 + lgrp * 16) ^ ((lrow & 7) << 4);
            int off1 = (row * 128 + 64 + lgrp * 16) ^ ((lrow & 7) << 4);
            short8 bk0 = *reinterpret_cast<const short8*>((const char*)ktc + off0);
            short8 bk1 = *reinterpret_cast<const short8*>((const char*)ktc + off1);
            floatx4 z = {0.f, 0.f, 0.f, 0.f};
            z = __builtin_amdgcn_mfma_f32_16x16x32_bf16(bk0, aq0, z, 0, 0, 0);
            z = __builtin_amdgcn_mfma_f32_16x16x32_bf16(bk1, aq1, z, 0, 0, 0);
            st[ni] = z;
        }
        __builtin_amdgcn_s_setprio(0);

        float pm[4][4];
#pragma unroll
        for (int ni = 0; ni < 4; ni++) {
            const float* mbp = reinterpret_cast<const float*>(&mb[ni]);
#pragma unroll
            for (int j = 0; j < 4; j++)
                pm[ni][j] = fmaf(st[ni][j], 0.125f, mbp[j]);
        }
        float pmax = pm[0][0];
#pragma unroll
        for (int ni = 0; ni < 4; ni++)
#pragma unroll
            for (int j = 0; j < 4; j++) pmax = fmaxf(pmax, pm[ni][j]);
        pmax = fmaxf(pmax, __shfl_xor(pmax, 16, 64));
        pmax = fmaxf(pmax, __shfl_xor(pmax, 32, 64));

        bool upd = !__all(pmax - mrun <= 8.0f);
        float fac = 1.0f;
        if (upd) {
            float mn = fmaxf(mrun, pmax);
            fac = __expf(mrun - mn);
            mrun = mn;
        }

        float p[4][4];
        float s = 0.f;
#pragma unroll
        for (int ni = 0; ni < 4; ni++)
#pragma unroll
            for (int j = 0; j < 4; j++) {
                float e = __expf(pm[ni][j] - mrun);
                p[ni][j] = e;
                s += e;
            }
        s += __shfl_xor(s, 16, 64);
        s += __shfl_xor(s, 32, 64);
        lrun = lrun * fac + s;

#pragma unroll
        for (int ni = 0; ni < 4; ni++) {
            bf16x4 pw;
#pragma unroll
            for (int j = 0; j < 4; j++) pw[j] = (short)f2bf_fast(p[ni][j]);
            unsigned woff = (unsigned)((lrow * 128 + ni * 32 + lgrp * 8) ^ ((lrow & 7) << 4));
            *reinterpret_cast<bf16x4*>((char*)pL[wid] + woff) = pw;
        }

        if (upd) {
            float f0 = __shfl(fac, lgrp * 4 + 0, 64);
            float f1 = __shfl(fac, lgrp * 4 + 1, 64);
            float f2 = __shfl(fac, lgrp * 4 + 2, 64);
            float f3 = __shfl(fac, lgrp * 4 + 3, 64);
#pragma unroll
            for (int nd = 0; nd < 4; nd++) {
                floatx4 tt = accO[nd];
                tt[0] *= f0; tt[1] *= f1; tt[2] *= f2; tt[3] *= f3;
                accO[nd] = tt;
            }
        }

        asm volatile("s_waitcnt lgkmcnt(0)" ::: "memory");
        __builtin_amdgcn_sched_barrier(0);

        unsigned ra0 = (unsigned)((lrow * 128 + lgrp * 16) ^ ((lrow & 7) << 4));
        unsigned ra1 = (unsigned)((lrow * 128 + 64 + lgrp * 16) ^ ((lrow & 7) << 4));
        short8 ap0 = *reinterpret_cast<const short8*>((const char*)pL[wid] + ra0);
        short8 ap1 = *reinterpret_cast<const short8*>((const char*)pL[wid] + ra1);

        short8 bv0[4], bv1[4];
#pragma unroll
        for (int nd = 0; nd < 4; nd++) {
            unsigned a = vva + nd * 2048;
            bf16x4 t0, t1, t2, t3;
            TRB16(t0, a, 0);
            TRB16(t1, a, 1024);
            TRB16(t2, a, 512);
            TRB16(t3, a, 1536);
            bv0[nd] = __builtin_shufflevector(t0, t1, 0, 1, 2, 3, 4, 5, 6, 7);
            bv1[nd] = __builtin_shufflevector(t2, t3, 0, 1, 2, 3, 4, 5, 6, 7);
        }
        asm volatile("s_waitcnt lgkmcnt(0)" ::: "memory");
        __builtin_amdgcn_sched_barrier(0);

        __builtin_amdgcn_s_setprio(1);
#pragma unroll
        for (int nd = 0; nd < 4; nd++) {
            accO[nd] = __builtin_amdgcn_mfma_f32_16x16x32_bf16(ap0, bv0[nd], accO[nd], 0, 0, 0);
            accO[nd] = __builtin_amdgcn_mfma_f32_16x16x32_bf16(ap1, bv1[nd], accO[nd], 0, 0, 0);
        }
        __builtin_amdgcn_s_setprio(0);

        asm volatile("" ::: "memory");
        __builtin_amdgcn_s_barrier();
        cur ^= 1;
    }

    float linv = 1.0f / lrun;
    float li[4];
#pragma unroll
    for (int j = 0; j < 4; j++) li[j] = __shfl(linv, lgrp * 4 + j, 64);
#pragma unroll
    for (int nd = 0; nd < 4; nd++)
#pragma unroll
        for (int j = 0; j < 4; j++) {
            int r = lgrp * 4 + j;
            float v = accO[nd][j] * li[j];
            O[(size_t)(b * S_ + qt * 64 + wid * 16 + r) * D_ + h * DK_ + nd * 16 + lrow] =
                f2bf_fast(v);
        }
}

// ---------------- residual + LayerNorm (torch: ddof=1, eps outside sqrt) ----
__global__ __launch_bounds__(256) void ln_kernel(const float* __restrict__ X,
                                                 const float* __restrict__ R,
                                                 const float* __restrict__ gam,
                                                 const float* __restrict__ bet,
                                                 float* __restrict__ outf,
                                                 u16* __restrict__ outb) {
    __shared__ float ws1[4], ws2[4];
    const int row = blockIdx.x, tid = threadIdx.x;
    const float4 x = reinterpret_cast<const float4*>(X + (size_t)row * D_)[tid];
    const float4 r = reinterpret_cast<const float4*>(R + (size_t)row * D_)[tid];
    float4 v; v.x = x.x + r.x; v.y = x.y + r.y; v.z = x.z + r.z; v.w = x.w + r.w;

    float s = v.x + v.y + v.z + v.w;
#pragma unroll
    for (int m = 32; m >= 1; m >>= 1) s += __shfl_xor(s, m, 64);
    if ((tid & 63) == 0) ws1[tid >> 6] = s;
    __syncthreads();
    float mean = (ws1[0] + ws1[1] + ws1[2] + ws1[3]) * (1.f / D_);

    float4 d; d.x = v.x - mean; d.y = v.y - mean; d.z = v.z - mean; d.w = v.w - mean;
    float q = d.x * d.x + d.y * d.y + d.z * d.z + d.w * d.w;
#pragma unroll
    for (int m = 32; m >= 1; m >>= 1) q += __shfl_xor(q, m, 64);
    if ((tid & 63) == 0) ws2[tid >> 6] = q;
    __syncthreads();
    float var = (ws2[0] + ws2[1] + ws2[2] + ws2[3]) * (1.f / (D_ - 1));
    float inv = 1.f / (sqrtf(var) + 1e-6f);

    const float4 g = reinterpret_cast<const float4*>(gam)[tid];
    const float4 bb = reinterpret_cast<const float4*>(bet)[tid];
    float4 o;
    o.x = g.x * d.x * inv + bb.x;
    o.y = g.y * d.y * inv + bb.y;
    o.z = g.z * d.z * inv + bb.z;
    o.w = g.w * d.w * inv + bb.w;
    if (outf) reinterpret_cast<float4*>(outf + (size_t)row * D_)[tid] = o;
    if (outb) {
        ushort4 ob;
        ob.x = f2bf(o.x); ob.y = f2bf(o.y); ob.z = f2bf(o.z); ob.w = f2bf(o.w);
        reinterpret_cast<ushort4*>(outb + (size_t)row * D_)[tid] = ob;
    }
}

// ---------------- launcher ----------------
extern "C" void kernel_launch(void* const* d_in, const int* in_sizes, int n_in,
                              void* d_out, int out_size, void* d_ws, size_t ws_size,
                              hipStream_t stream) {
    const float* x    = (const float*)d_in[0];
    const int*   mask = (const int*)d_in[1];
    const float* wq   = (const float*)d_in[2];
    const float* bq   = (const float*)d_in[3];
    const float* wk   = (const float*)d_in[4];
    const float* bk   = (const float*)d_in[5];
    const float* wv   = (const float*)d_in[6];
    const float* bv   = (const float*)d_in[7];
    const float* wo   = (const float*)d_in[8];
    const float* bo   = (const float*)d_in[9];
    const float* g1   = (const float*)d_in[10];
    const float* b1   = (const float*)d_in[11];
    const float* g2   = (const float*)d_in[12];
    const float* b2   = (const float*)d_in[13];
    const float* w1   = (const float*)d_in[14];
    const float* bf1  = (const float*)d_in[15];
    const float* w2   = (const float*)d_in[16];
    const float* bf2  = (const float*)d_in[17];
    float* out = (float*)d_out;

    char* ws = (char*)d_ws;
    size_t off = 0;
    auto alloc = [&](size_t bytes) -> void* {
        void* p = ws + off;
        off += (bytes + 255) & ~(size_t)255;
        return p;
    };
    u16*   xb    = (u16*)  alloc((size_t)M_ * D_ * 2);
    u16*   wqkvb = (u16*)  alloc((size_t)3 * D_ * D_ * 2);
    u16*   wob   = (u16*)  alloc((size_t)D_ * D_ * 2);
    u16*   w1b   = (u16*)  alloc((size_t)DFF_ * D_ * 2);
    u16*   w2b   = (u16*)  alloc((size_t)D_ * DFF_ * 2);
    float* bqkv  = (float*)alloc((size_t)3 * D_ * 4);
    float* mbias = (float*)alloc((size_t)B_ * S_ * 4);
    u16*   qkvb  = (u16*)  alloc((size_t)M_ * 3 * D_ * 2);
    u16*   cvb   = (u16*)  alloc((size_t)M_ * D_ * 2);
    float* projf = (float*)alloc((size_t)M_ * D_ * 4);
    float* hdf   = (float*)alloc((size_t)M_ * D_ * 4);
    u16*   hdb   = (u16*)  alloc((size_t)M_ * D_ * 2);
    u16*   ff1b  = (u16*)  alloc((size_t)M_ * DFF_ * 2);
    float* ff2f  = (float*)alloc((size_t)M_ * D_ * 4);

    cvt_all<<<2048, 256, 0, stream>>>(x, wq, wk, wv, wo, w1, w2,
                                      xb, wqkvb, wob, w1b, w2b);
    prep_misc<<<28, 256, 0, stream>>>(bq, bk, bv, mask, bqkv, mbias);

    // fused QKV projection: [4096,3072,1024] on 256x256 8-phase
    gemm256_bt<0><<<dim3(M_ / 256, 3 * D_ / 256), 512, 0, stream>>>(
        xb, wqkvb, bqkv, qkvb, 3 * D_, D_);

    // attention
    attn_kernel<<<dim3(S_ / 64, B_ * H_), 256, 0, stream>>>(qkvb, mbias, cvb);

    // output projection: [4096,1024,1024] -> fp32 (128x128)
    gemm_bt<1><<<dim3(M_ / 128, D_ / 128), 256, 0, stream>>>(
        cvb, wob, bo, projf, nullptr, D_, D_);

    // residual + LN1
    ln_kernel<<<M_, 256, 0, stream>>>(x, projf, g1, b1, hdf, hdb);

    // FFN1 + GELU: [4096,4096,1024] on 256x256 8-phase
    gemm256_bt<2><<<dim3(M_ / 256, DFF_ / 256), 512, 0, stream>>>(
        hdb, w1b, bf1, ff1b, DFF_, D_);

    // FFN2: [4096,1024,4096] -> fp32 (128x128)
    gemm_bt<1><<<dim3(M_ / 128, D_ / 128), 256, 0, stream>>>(
        ff1b, w2b, bf2, ff2f, nullptr, D_, DFF_);

    // residual + LN2 -> out
    ln_kernel<<<M_, 256, 0, stream>>>(hdf, ff2f, g2, b2, out, nullptr);
}

// Round 6
// 424.395 us; speedup vs baseline: 1.3231x; 1.0737x over previous
//
#include <hip/hip_runtime.h>
#include <hip/hip_bf16.h>

// ---------------- constants (problem shape) ----------------
#define B_   2
#define S_   2048
#define D_   1024
#define H_   16
#define DK_  64
#define DFF_ 4096
#define M_   (B_*S_)   // 4096 rows

typedef unsigned short u16;
typedef __attribute__((ext_vector_type(8))) short short8;
typedef __attribute__((ext_vector_type(4))) short bf16x4;
typedef __attribute__((ext_vector_type(4))) float floatx4;

// fp32 -> bf16 round-to-nearest-even (manual, used in GEMM epilogue)
__device__ __forceinline__ u16 f2bf(float f) {
    union { float f; unsigned u; } v; v.f = f;
    unsigned r = v.u + 0x7fffu + ((v.u >> 16) & 1u);
    return (u16)(r >> 16);
}
// compiler path (emits v_cvt_pk_bf16_f32 for pairs)
__device__ __forceinline__ u16 f2bf_fast(float f) {
    __hip_bfloat16 h = __float2bfloat16(f);
    return *reinterpret_cast<u16*>(&h);
}

// fast 2^x (v_exp_f32 computes 2^x natively)
__device__ __forceinline__ float exp2_fast(float f) {
    return __builtin_amdgcn_exp2f(f);
}

// async global->LDS, 16B per lane. LDS dest must be wave-uniform base.
__device__ __forceinline__ void g2l16(const u16* g, u16* l) {
    __builtin_amdgcn_global_load_lds((const __attribute__((address_space(1))) void*)g,
                                     (__attribute__((address_space(3))) void*)l,
                                     16, 0, 0);
}

__device__ __forceinline__ unsigned lds_off(const void* p) {
    return (unsigned)(unsigned long long)p;
}

#define TRB16(dst, va, IMM)                                                    \
    asm volatile("ds_read_b64_tr_b16 %0, %1 offset:" #IMM                      \
                 : "=v"(dst) : "v"(va))

// ---------------- fused fp32->bf16 conversion of x + all weights ----------------
__global__ __launch_bounds__(256) void cvt_all(
    const float* __restrict__ x,  const float* __restrict__ wq,
    const float* __restrict__ wk, const float* __restrict__ wv,
    const float* __restrict__ wo, const float* __restrict__ w1,
    const float* __restrict__ w2,
    u16* __restrict__ xb, u16* __restrict__ wqkvb, u16* __restrict__ wob,
    u16* __restrict__ w1b, u16* __restrict__ w2b) {
    for (int i = blockIdx.x * 256 + threadIdx.x; i < 4194304;
         i += gridDim.x * 256) {
        const float* s; u16* d; int off;
        if (i < 1048576)      { s = x;  d = xb;    off = i; }
        else if (i < 1310720) { s = wq; d = wqkvb; off = i - 1048576; }
        else if (i < 1572864) { s = wk; d = wqkvb + 1048576; off = i - 1310720; }
        else if (i < 1835008) { s = wv; d = wqkvb + 2097152; off = i - 1572864; }
        else if (i < 2097152) { s = wo; d = wob;   off = i - 1835008; }
        else if (i < 3145728) { s = w1; d = w1b;   off = i - 2097152; }
        else                  { s = w2; d = w2b;   off = i - 3145728; }
        float4 v = reinterpret_cast<const float4*>(s)[off];
        ushort4 o;
        o.x = f2bf(v.x); o.y = f2bf(v.y); o.z = f2bf(v.z); o.w = f2bf(v.w);
        reinterpret_cast<ushort4*>(d)[off] = o;
    }
}

// bias concat (3072) + mask->mbias pre-scaled by log2(e) (4096). grid 28x256
__global__ __launch_bounds__(256) void prep_misc(const float* __restrict__ bq,
                                                 const float* __restrict__ bk,
                                                 const float* __restrict__ bv,
                                                 const int* __restrict__ mask,
                                                 float* __restrict__ bqkv,
                                                 float* __restrict__ mbias) {
    int i = blockIdx.x * 256 + threadIdx.x;
    if (i < 3 * D_) {
        float v = (i < D_) ? bq[i] : (i < 2 * D_) ? bk[i - D_] : bv[i - 2 * D_];
        bqkv[i] = v;
    } else if (i < 3 * D_ + B_ * S_) {
        int k = i - 3 * D_;
        mbias[k] = (mask[k] == 0) ? -1.44269504e9f : 0.0f;   // log2-domain
    }
}

// ---------------- 256x256 8-phase GEMM: C[M,N] = A[M,K] @ B[N,K]^T + bias ----
// EPI: 0 = bias, store bf16 ; 2 = bias + erf-GELU, store bf16
template <int EPI>
__global__ __launch_bounds__(512, 2) void gemm256_bt(const u16* __restrict__ A,
                                                     const u16* __restrict__ Bw,
                                                     const float* __restrict__ bias,
                                                     u16* __restrict__ Cb,
                                                     int N, int K) {
    __shared__ alignas(16) u16 sA[2][2][8192];   // [parity][half][128 rows x 64 k]
    __shared__ alignas(16) u16 sB[2][2][8192];
    const int tid = threadIdx.x;
    const int wid = tid >> 6, lane = tid & 63;
    const int lrow = lane & 15, lgrp = lane >> 4;
    const int wm = wid >> 2, wn = wid & 3;       // 2 x 4 wave grid

    // bijective XCD swizzle (m204)
    const int nbx = gridDim.x;
    const int nwg = nbx * gridDim.y;
    const int orig = blockIdx.y * nbx + blockIdx.x;
    const int qd = nwg >> 3, rr = nwg & 7, xc = orig & 7, oi = orig >> 3;
    const int swz = (xc < rr ? xc * (qd + 1) : rr * (qd + 1) + (xc - rr) * qd) + oi;
    const int m0 = (swz % nbx) * 256, n0 = (swz / nbx) * 256;

    const u16* Ab = A + (size_t)m0 * K;
    const u16* Bb = Bw + (size_t)n0 * K;
    const int T = K >> 6;

    const int c0 = (wid * 2 + 0) * 64 + lane;
    const int c1 = (wid * 2 + 1) * 64 + lane;
    const int r0 = c0 >> 3, g0 = c0 & 7;
    const int r1 = c1 >> 3, g1 = c1 & 7;
    const size_t so0 = (size_t)r0 * K + (size_t)((g0 ^ (r0 & 7)) * 8);
    const size_t so1 = (size_t)r1 * K + (size_t)((g1 ^ (r1 & 7)) * 8);
    const int d0 = (wid * 2 + 0) * 512;
    const int d1 = (wid * 2 + 1) * 512;

    auto stageA = [&](int par, int half, int kt) {
        const u16* src = Ab + (size_t)(half * 128) * K + kt * 64;
        g2l16(src + so0, &sA[par][half][d0]);
        g2l16(src + so1, &sA[par][half][d1]);
    };
    auto stageB = [&](int par, int half, int kt) {
        const u16* src = Bb + (size_t)(half * 128) * K + kt * 64;
        g2l16(src + so0, &sB[par][half][d0]);
        g2l16(src + so1, &sB[par][half][d1]);
    };

    stageA(0, 0, 0); stageA(0, 1, 0);
    stageB(0, 0, 0); stageB(0, 1, 0);
    if (T > 1) { stageB(1, 0, 1); stageB(1, 1, 1); }
    asm volatile("s_waitcnt vmcnt(4)" ::: "memory");
    asm volatile("s_barrier" ::: "memory");

    floatx4 acc[8][4] = {};
    const int rbase = (wn & 1) * 64;
    const int bhalf = wn >> 1;

    for (int t = 0; t < T; t++) {
        const int par = t & 1;
        const char* baseA = (const char*)&sA[par][wm][0];
        const char* baseB = (const char*)&sB[par][bhalf][0];
        short8 bfr[4][2];
#pragma unroll
        for (int ph = 0; ph < 4; ph++) {
            if (ph == 0) {
#pragma unroll
                for (int nj = 0; nj < 4; nj++) {
                    int rb = rbase + nj * 16 + lrow;
#pragma unroll
                    for (int kk = 0; kk < 2; kk++) {
                        int off = rb * 128 + (((kk * 4 + lgrp) ^ (lrow & 7)) * 16);
                        bfr[nj][kk] = *reinterpret_cast<const short8*>(baseB + off);
                    }
                }
            }
            short8 af[2][2];
#pragma unroll
            for (int a = 0; a < 2; a++) {
                int ra = (2 * ph + a) * 16 + lrow;
#pragma unroll
                for (int kk = 0; kk < 2; kk++) {
                    int off = ra * 128 + (((kk * 4 + lgrp) ^ (lrow & 7)) * 16);
                    af[a][kk] = *reinterpret_cast<const short8*>(baseA + off);
                }
            }
            if (ph == 0) { if (t + 1 < T) stageA(par ^ 1, 0, t + 1); }
            if (ph == 1) { if (t + 1 < T) stageA(par ^ 1, 1, t + 1); }
            if (ph == 2) { if (t + 2 < T) stageB(par, 0, t + 2); }
            if (ph == 3) { if (t + 2 < T) stageB(par, 1, t + 2); }

            asm volatile("s_barrier" ::: "memory");
            asm volatile("s_waitcnt lgkmcnt(0)" ::: "memory");
            __builtin_amdgcn_sched_barrier(0);

            __builtin_amdgcn_s_setprio(1);
#pragma unroll
            for (int a = 0; a < 2; a++)
#pragma unroll
                for (int nj = 0; nj < 4; nj++) {
                    acc[2 * ph + a][nj] = __builtin_amdgcn_mfma_f32_16x16x32_bf16(
                        af[a][0], bfr[nj][0], acc[2 * ph + a][nj], 0, 0, 0);
                    acc[2 * ph + a][nj] = __builtin_amdgcn_mfma_f32_16x16x32_bf16(
                        af[a][1], bfr[nj][1], acc[2 * ph + a][nj], 0, 0, 0);
                }
            __builtin_amdgcn_s_setprio(0);

            if (ph == 3) {
                if (t >= T - 3) asm volatile("s_waitcnt vmcnt(0)" ::: "memory");
                else            asm volatile("s_waitcnt vmcnt(4)" ::: "memory");
            }
            asm volatile("s_barrier" ::: "memory");
        }
    }

#pragma unroll
    for (int mi = 0; mi < 8; mi++) {
        int row = m0 + wm * 128 + mi * 16 + lgrp * 4;
#pragma unroll
        for (int nj = 0; nj < 4; nj++) {
            int col = n0 + wn * 64 + nj * 16 + lrow;
            float bc = bias[col];
#pragma unroll
            for (int j = 0; j < 4; j++) {
                float v = acc[mi][nj][j] + bc;
                if (EPI == 2) v = 0.5f * v * (1.0f + erff(v * 0.70710678118654752f));
                Cb[(size_t)(row + j) * N + col] = f2bf(v);
            }
        }
    }
}

// ---------------- 128x128 GEMM (m97 structure) for small-N shapes ----------
template <int EPI>
__global__ __launch_bounds__(256) void gemm_bt(const u16* __restrict__ A,
                                               const u16* __restrict__ Bw,
                                               const float* __restrict__ bias,
                                               float* __restrict__ Cf,
                                               u16* __restrict__ Cb,
                                               int N, int K) {
    __shared__ u16 sA[128 * 32];
    __shared__ u16 sB[128 * 32];
    const int tid = threadIdx.x;
    const int wid = tid >> 6, lane = tid & 63;
    const int lrow = lane & 15, lgrp = lane >> 4;

    const int nbx = gridDim.x;
    const int nwg = nbx * gridDim.y;
    const int orig = blockIdx.y * nbx + blockIdx.x;
    const int qd = nwg >> 3, rr = nwg & 7, xc = orig & 7, oi = orig >> 3;
    const int swz = (xc < rr ? xc * (qd + 1) : rr * (qd + 1) + (xc - rr) * qd) + oi;
    const int m0 = (swz % nbx) * 128, n0 = (swz / nbx) * 128;

    const int wm = wid >> 1, wn = wid & 1;
    const int ar = lane >> 2, ac = lane & 3;

    floatx4 acc[4][4] = {};
    const u16* Ab = A + (size_t)m0 * K;
    const u16* Bb = Bw + (size_t)n0 * K;

    for (int k0 = 0; k0 < K; k0 += 32) {
#pragma unroll
        for (int i = 0; i < 2; i++) {
            int seg = wid * 2 + i;
            int row = seg * 16 + ar;
            g2l16(Ab + (size_t)row * K + k0 + ac * 8, &sA[seg * 512]);
            g2l16(Bb + (size_t)row * K + k0 + ac * 8, &sB[seg * 512]);
        }
        __syncthreads();
        short8 af[4], bfr[4];
#pragma unroll
        for (int mi = 0; mi < 4; mi++)
            af[mi] = *reinterpret_cast<const short8*>(
                &sA[(wm * 64 + mi * 16 + lrow) * 32 + lgrp * 8]);
#pragma unroll
        for (int ni = 0; ni < 4; ni++)
            bfr[ni] = *reinterpret_cast<const short8*>(
                &sB[(wn * 64 + ni * 16 + lrow) * 32 + lgrp * 8]);
#pragma unroll
        for (int mi = 0; mi < 4; mi++)
#pragma unroll
            for (int ni = 0; ni < 4; ni++)
                acc[mi][ni] = __builtin_amdgcn_mfma_f32_16x16x32_bf16(
                    af[mi], bfr[ni], acc[mi][ni], 0, 0, 0);
        __syncthreads();
    }

#pragma unroll
    for (int mi = 0; mi < 4; mi++) {
        int row = m0 + wm * 64 + mi * 16 + lgrp * 4;
#pragma unroll
        for (int ni = 0; ni < 4; ni++) {
            int col = n0 + wn * 64 + ni * 16 + lrow;
            float bc = bias[col];
#pragma unroll
            for (int j = 0; j < 4; j++) {
                float v = acc[mi][ni][j] + bc;
                if (EPI == 1)
                    Cf[(size_t)(row + j) * N + col] = v;
                else
                    Cb[(size_t)(row + j) * N + col] = f2bf(v);
            }
        }
    }
}

// ---------------- flash attention v4 -----------------------------------------
// 8 waves, 128 q-rows/block, 512 wgs. Swapped QK^T (lane-local softmax),
// exp2-domain softmax, early V tr-read issue, defer-max, double-buffered
// async K/V staging with counted vmcnt(2).
__global__ __launch_bounds__(512) void attn_kernel(const u16* __restrict__ QKV,
                                                   const float* __restrict__ mbias,
                                                   u16* __restrict__ O) {
    const int SD = 3 * D_;
    __shared__ alignas(16) u16 ktL[2][4096];   // [buf][64 kv][64 d] src-swizzled
    __shared__ alignas(16) u16 vtL[2][4096];   // [buf] tr-subtiled V
    __shared__ alignas(16) u16 pL[8][1024];    // per-wave P [16 q][64 kv] swizzled

    const int orig = blockIdx.y * gridDim.x + blockIdx.x;   // 512 wgs
    const int swz = (orig & 7) * 64 + (orig >> 3);
    const int qt = swz & 15, bh = swz >> 4;
    const int b = bh >> 4, h = bh & 15;

    const int tid = threadIdx.x, wid = tid >> 6, lane = tid & 63;
    const int lrow = lane & 15, lgrp = lane >> 4;

    const u16* Qp = QKV + h * DK_;
    const u16* Kp = QKV + D_ + h * DK_;
    const u16* Vp = QKV + 2 * D_ + h * DK_;
    const float* mbrow = mbias + b * S_;

    const int qr = qt * 128 + wid * 16 + lrow;
    const u16* qrow = Qp + (size_t)(b * S_ + qr) * SD;
    short8 aq0 = *reinterpret_cast<const short8*>(qrow + lgrp * 8);
    short8 aq1 = *reinterpret_cast<const short8*>(qrow + 32 + lgrp * 8);

    // staging source pointers (verified pattern, seg = wid, 1 chunk/lane/buf)
    const int q8 = wid * 64 + lane;
    const int krow = q8 >> 3, kcb = q8 & 7;
    const u16* kq = Kp + (size_t)(b * S_ + krow) * SD + ((kcb ^ (krow & 7)) * 8);
    const int ov = wid * 512 + lane * 8;
    const int vk = ((ov >> 6) & 7) * 8 + ((ov >> 9) & 1) * 4 + ((ov >> 4) & 3);
    const int vd = (ov >> 10) * 16 + (ov & 8);
    const u16* vq = Vp + (size_t)(b * S_ + vk) * SD + vd;

    auto issue = [&](int bufIdx) {
        g2l16(kq, &ktL[bufIdx][wid * 512]);
        g2l16(vq, &vtL[bufIdx][wid * 512]);
        kq += 64 * SD;
        vq += 64 * SD;
    };

    floatx4 accO[4] = {};
    float mrun = -1e30f, lrun = 0.f;
    const float SC2 = 0.18033688011112042f;    // 0.125 * log2(e)

    issue(0);
    int cur = 0;
    for (int t = 0; t < S_ / 64; t++) {
        const int kv0 = t * 64;
        if (t < S_ / 64 - 1) {
            issue(cur ^ 1);
            asm volatile("s_waitcnt vmcnt(2)" ::: "memory");
        } else {
            asm volatile("s_waitcnt vmcnt(0)" ::: "memory");
        }
        __builtin_amdgcn_s_barrier();
        asm volatile("" ::: "memory");

        const u16* ktc = ktL[cur];
        const unsigned vva = lds_off(vtL[cur]) + lane * 8;

        float4 mb[4];
#pragma unroll
        for (int ni = 0; ni < 4; ni++)
            mb[ni] = *reinterpret_cast<const float4*>(mbrow + kv0 + ni * 16 + lgrp * 4);

        // ---- swapped QK^T: S^T[kv][q] ----
        floatx4 st[4];
        __builtin_amdgcn_s_setprio(1);
#pragma unroll
        for (int ni = 0; ni < 4; ni++) {
            int row = ni * 16 + lrow;
            int off0 = (row * 128 + lgrp * 16) ^ ((lrow & 7) << 4);
            int off1 = (row * 128 + 64 + lgrp * 16) ^ ((lrow & 7) << 4);
            short8 bk0 = *reinterpret_cast<const short8*>((const char*)ktc + off0);
            short8 bk1 = *reinterpret_cast<const short8*>((const char*)ktc + off1);
            floatx4 z = {0.f, 0.f, 0.f, 0.f};
            z = __builtin_amdgcn_mfma_f32_16x16x32_bf16(bk0, aq0, z, 0, 0, 0);
            z = __builtin_amdgcn_mfma_f32_16x16x32_bf16(bk1, aq1, z, 0, 0, 0);
            st[ni] = z;
        }
        __builtin_amdgcn_s_setprio(0);

        // ---- early V tr-read issue: latency hides under softmax ----
        bf16x4 vt0[4], vt1[4], vt2[4], vt3[4];
#pragma unroll
        for (int nd = 0; nd < 4; nd++) {
            unsigned a = vva + nd * 2048;
            TRB16(vt0[nd], a, 0);
            TRB16(vt1[nd], a, 1024);
            TRB16(vt2[nd], a, 512);
            TRB16(vt3[nd], a, 1536);
        }

        // ---- softmax (log2 domain, lane-local) ----
        float pm[4][4];
#pragma unroll
        for (int ni = 0; ni < 4; ni++) {
            const float* mbp = reinterpret_cast<const float*>(&mb[ni]);
#pragma unroll
            for (int j = 0; j < 4; j++)
                pm[ni][j] = fmaf(st[ni][j], SC2, mbp[j]);
        }
        float pmax = pm[0][0];
#pragma unroll
        for (int ni = 0; ni < 4; ni++)
#pragma unroll
            for (int j = 0; j < 4; j++) pmax = fmaxf(pmax, pm[ni][j]);
        pmax = fmaxf(pmax, __shfl_xor(pmax, 16, 64));
        pmax = fmaxf(pmax, __shfl_xor(pmax, 32, 64));

        bool upd = !__all(pmax - mrun <= 11.5f);
        float fac = 1.0f;
        if (upd) {
            float mn = fmaxf(mrun, pmax);
            fac = exp2_fast(mrun - mn);
            mrun = mn;
        }

        float p[4][4];
        float s = 0.f;
#pragma unroll
        for (int ni = 0; ni < 4; ni++)
#pragma unroll
            for (int j = 0; j < 4; j++) {
                float e = exp2_fast(pm[ni][j] - mrun);
                p[ni][j] = e;
                s += e;
            }
        s += __shfl_xor(s, 16, 64);
        s += __shfl_xor(s, 32, 64);
        lrun = lrun * fac + s;

        // ---- P -> LDS [q=lrow][kv] XOR-swizzled ----
#pragma unroll
        for (int ni = 0; ni < 4; ni++) {
            bf16x4 pw;
#pragma unroll
            for (int j = 0; j < 4; j++) pw[j] = (short)f2bf_fast(p[ni][j]);
            unsigned woff = (unsigned)((lrow * 128 + ni * 32 + lgrp * 8) ^ ((lrow & 7) << 4));
            *reinterpret_cast<bf16x4*>((char*)pL[wid] + woff) = pw;
        }

        if (upd) {
            float f0 = __shfl(fac, lgrp * 4 + 0, 64);
            float f1 = __shfl(fac, lgrp * 4 + 1, 64);
            float f2 = __shfl(fac, lgrp * 4 + 2, 64);
            float f3 = __shfl(fac, lgrp * 4 + 3, 64);
#pragma unroll
            for (int nd = 0; nd < 4; nd++) {
                floatx4 tt = accO[nd];
                tt[0] *= f0; tt[1] *= f1; tt[2] *= f2; tt[3] *= f3;
                accO[nd] = tt;
            }
        }

        asm volatile("s_waitcnt lgkmcnt(0)" ::: "memory");
        __builtin_amdgcn_sched_barrier(0);

        // P A-frags (plain reads; compiler inserts its own waits)
        unsigned ra0 = (unsigned)((lrow * 128 + lgrp * 16) ^ ((lrow & 7) << 4));
        unsigned ra1 = (unsigned)((lrow * 128 + 64 + lgrp * 16) ^ ((lrow & 7) << 4));
        short8 ap0 = *reinterpret_cast<const short8*>((const char*)pL[wid] + ra0);
        short8 ap1 = *reinterpret_cast<const short8*>((const char*)pL[wid] + ra1);

        __builtin_amdgcn_s_setprio(1);
#pragma unroll
        for (int nd = 0; nd < 4; nd++) {
            short8 bv0 = __builtin_shufflevector(vt0[nd], vt1[nd], 0, 1, 2, 3, 4, 5, 6, 7);
            short8 bv1 = __builtin_shufflevector(vt2[nd], vt3[nd], 0, 1, 2, 3, 4, 5, 6, 7);
            accO[nd] = __builtin_amdgcn_mfma_f32_16x16x32_bf16(ap0, bv0, accO[nd], 0, 0, 0);
            accO[nd] = __builtin_amdgcn_mfma_f32_16x16x32_bf16(ap1, bv1, accO[nd], 0, 0, 0);
        }
        __builtin_amdgcn_s_setprio(0);

        asm volatile("" ::: "memory");
        __builtin_amdgcn_s_barrier();
        cur ^= 1;
    }

    float linv = 1.0f / lrun;
    float li[4];
#pragma unroll
    for (int j = 0; j < 4; j++) li[j] = __shfl(linv, lgrp * 4 + j, 64);
#pragma unroll
    for (int nd = 0; nd < 4; nd++)
#pragma unroll
        for (int j = 0; j < 4; j++) {
            int r = lgrp * 4 + j;
            float v = accO[nd][j] * li[j];
            O[(size_t)(b * S_ + qt * 128 + wid * 16 + r) * D_ + h * DK_ + nd * 16 + lrow] =
                f2bf_fast(v);
        }
}

// ---------------- residual + LayerNorm (torch: ddof=1, eps outside sqrt) ----
__global__ __launch_bounds__(256) void ln_kernel(const float* __restrict__ X,
                                                 const float* __restrict__ R,
                                                 const float* __restrict__ gam,
                                                 const float* __restrict__ bet,
                                                 float* __restrict__ outf,
                                                 u16* __restrict__ outb) {
    __shared__ float ws1[4], ws2[4];
    const int row = blockIdx.x, tid = threadIdx.x;
    const float4 x = reinterpret_cast<const float4*>(X + (size_t)row * D_)[tid];
    const float4 r = reinterpret_cast<const float4*>(R + (size_t)row * D_)[tid];
    float4 v; v.x = x.x + r.x; v.y = x.y + r.y; v.z = x.z + r.z; v.w = x.w + r.w;

    float s = v.x + v.y + v.z + v.w;
#pragma unroll
    for (int m = 32; m >= 1; m >>= 1) s += __shfl_xor(s, m, 64);
    if ((tid & 63) == 0) ws1[tid >> 6] = s;
    __syncthreads();
    float mean = (ws1[0] + ws1[1] + ws1[2] + ws1[3]) * (1.f / D_);

    float4 d; d.x = v.x - mean; d.y = v.y - mean; d.z = v.z - mean; d.w = v.w - mean;
    float q = d.x * d.x + d.y * d.y + d.z * d.z + d.w * d.w;
#pragma unroll
    for (int m = 32; m >= 1; m >>= 1) q += __shfl_xor(q, m, 64);
    if ((tid & 63) == 0) ws2[tid >> 6] = q;
    __syncthreads();
    float var = (ws2[0] + ws2[1] + ws2[2] + ws2[3]) * (1.f / (D_ - 1));
    float inv = 1.f / (sqrtf(var) + 1e-6f);

    const float4 g = reinterpret_cast<const float4*>(gam)[tid];
    const float4 bb = reinterpret_cast<const float4*>(bet)[tid];
    float4 o;
    o.x = g.x * d.x * inv + bb.x;
    o.y = g.y * d.y * inv + bb.y;
    o.z = g.z * d.z * inv + bb.z;
    o.w = g.w * d.w * inv + bb.w;
    if (outf) reinterpret_cast<float4*>(outf + (size_t)row * D_)[tid] = o;
    if (outb) {
        ushort4 ob;
        ob.x = f2bf(o.x); ob.y = f2bf(o.y); ob.z = f2bf(o.z); ob.w = f2bf(o.w);
        reinterpret_cast<ushort4*>(outb + (size_t)row * D_)[tid] = ob;
    }
}

// ---------------- launcher ----------------
extern "C" void kernel_launch(void* const* d_in, const int* in_sizes, int n_in,
                              void* d_out, int out_size, void* d_ws, size_t ws_size,
                              hipStream_t stream) {
    const float* x    = (const float*)d_in[0];
    const int*   mask = (const int*)d_in[1];
    const float* wq   = (const float*)d_in[2];
    const float* bq   = (const float*)d_in[3];
    const float* wk   = (const float*)d_in[4];
    const float* bk   = (const float*)d_in[5];
    const float* wv   = (const float*)d_in[6];
    const float* bv   = (const float*)d_in[7];
    const float* wo   = (const float*)d_in[8];
    const float* bo   = (const float*)d_in[9];
    const float* g1   = (const float*)d_in[10];
    const float* b1   = (const float*)d_in[11];
    const float* g2   = (const float*)d_in[12];
    const float* b2   = (const float*)d_in[13];
    const float* w1   = (const float*)d_in[14];
    const float* bf1  = (const float*)d_in[15];
    const float* w2   = (const float*)d_in[16];
    const float* bf2  = (const float*)d_in[17];
    float* out = (float*)d_out;

    char* ws = (char*)d_ws;
    size_t off = 0;
    auto alloc = [&](size_t bytes) -> void* {
        void* p = ws + off;
        off += (bytes + 255) & ~(size_t)255;
        return p;
    };
    u16*   xb    = (u16*)  alloc((size_t)M_ * D_ * 2);
    u16*   wqkvb = (u16*)  alloc((size_t)3 * D_ * D_ * 2);
    u16*   wob   = (u16*)  alloc((size_t)D_ * D_ * 2);
    u16*   w1b   = (u16*)  alloc((size_t)DFF_ * D_ * 2);
    u16*   w2b   = (u16*)  alloc((size_t)D_ * DFF_ * 2);
    float* bqkv  = (float*)alloc((size_t)3 * D_ * 4);
    float* mbias = (float*)alloc((size_t)B_ * S_ * 4);
    u16*   qkvb  = (u16*)  alloc((size_t)M_ * 3 * D_ * 2);
    u16*   cvb   = (u16*)  alloc((size_t)M_ * D_ * 2);
    float* projf = (float*)alloc((size_t)M_ * D_ * 4);
    float* hdf   = (float*)alloc((size_t)M_ * D_ * 4);
    u16*   hdb   = (u16*)  alloc((size_t)M_ * D_ * 2);
    u16*   ff1b  = (u16*)  alloc((size_t)M_ * DFF_ * 2);
    float* ff2f  = (float*)alloc((size_t)M_ * D_ * 4);

    cvt_all<<<2048, 256, 0, stream>>>(x, wq, wk, wv, wo, w1, w2,
                                      xb, wqkvb, wob, w1b, w2b);
    prep_misc<<<28, 256, 0, stream>>>(bq, bk, bv, mask, bqkv, mbias);

    // fused QKV projection: [4096,3072,1024] on 256x256 8-phase
    gemm256_bt<0><<<dim3(M_ / 256, 3 * D_ / 256), 512, 0, stream>>>(
        xb, wqkvb, bqkv, qkvb, 3 * D_, D_);

    // attention: 8 waves, 128 q-rows per block
    attn_kernel<<<dim3(S_ / 128, B_ * H_), 512, 0, stream>>>(qkvb, mbias, cvb);

    // output projection: [4096,1024,1024] -> fp32 (128x128)
    gemm_bt<1><<<dim3(M_ / 128, D_ / 128), 256, 0, stream>>>(
        cvb, wob, bo, projf, nullptr, D_, D_);

    // residual + LN1
    ln_kernel<<<M_, 256, 0, stream>>>(x, projf, g1, b1, hdf, hdb);

    // FFN1 + GELU: [4096,4096,1024] on 256x256 8-phase
    gemm256_bt<2><<<dim3(M_ / 256, DFF_ / 256), 512, 0, stream>>>(
        hdb, w1b, bf1, ff1b, DFF_, D_);

    // FFN2: [4096,1024,4096] -> fp32 (128x128)
    gemm_bt<1><<<dim3(M_ / 128, D_ / 128), 256, 0, stream>>>(
        ff1b, w2b, bf2, ff2f, nullptr, D_, DFF_);

    // residual + LN2 -> out
    ln_kernel<<<M_, 256, 0, stream>>>(hdf, ff2f, g2, b2, out, nullptr);
}

// Round 7
// 410.588 us; speedup vs baseline: 1.3676x; 1.0336x over previous
//
#include <hip/hip_runtime.h>
#include <hip/hip_bf16.h>

// ---------------- constants (problem shape) ----------------
#define B_   2
#define S_   2048
#define D_   1024
#define H_   16
#define DK_  64
#define DFF_ 4096
#define M_   (B_*S_)   // 4096 rows

typedef unsigned short u16;
typedef __attribute__((ext_vector_type(8))) short short8;
typedef __attribute__((ext_vector_type(4))) short bf16x4;
typedef __attribute__((ext_vector_type(4))) float floatx4;

// fp32 -> bf16 round-to-nearest-even (manual, used in GEMM epilogue)
__device__ __forceinline__ u16 f2bf(float f) {
    union { float f; unsigned u; } v; v.f = f;
    unsigned r = v.u + 0x7fffu + ((v.u >> 16) & 1u);
    return (u16)(r >> 16);
}
// compiler path (emits v_cvt_pk_bf16_f32 for pairs)
__device__ __forceinline__ u16 f2bf_fast(float f) {
    __hip_bfloat16 h = __float2bfloat16(f);
    return *reinterpret_cast<u16*>(&h);
}

// fast 2^x (v_exp_f32 computes 2^x natively)
__device__ __forceinline__ float exp2_fast(float f) {
    return __builtin_amdgcn_exp2f(f);
}

// async global->LDS, 16B per lane. LDS dest must be wave-uniform base.
__device__ __forceinline__ void g2l16(const u16* g, u16* l) {
    __builtin_amdgcn_global_load_lds((const __attribute__((address_space(1))) void*)g,
                                     (__attribute__((address_space(3))) void*)l,
                                     16, 0, 0);
}

__device__ __forceinline__ unsigned lds_off(const void* p) {
    return (unsigned)(unsigned long long)p;
}

#define TRB16(dst, va, IMM)                                                    \
    asm volatile("ds_read_b64_tr_b16 %0, %1 offset:" #IMM                      \
                 : "=v"(dst) : "v"(va))

// ---------------- fused fp32->bf16 conversion of x + all weights ----------------
__global__ __launch_bounds__(256) void cvt_all(
    const float* __restrict__ x,  const float* __restrict__ wq,
    const float* __restrict__ wk, const float* __restrict__ wv,
    const float* __restrict__ wo, const float* __restrict__ w1,
    const float* __restrict__ w2,
    u16* __restrict__ xb, u16* __restrict__ wqkvb, u16* __restrict__ wob,
    u16* __restrict__ w1b, u16* __restrict__ w2b) {
    for (int i = blockIdx.x * 256 + threadIdx.x; i < 4194304;
         i += gridDim.x * 256) {
        const float* s; u16* d; int off;
        if (i < 1048576)      { s = x;  d = xb;    off = i; }
        else if (i < 1310720) { s = wq; d = wqkvb; off = i - 1048576; }
        else if (i < 1572864) { s = wk; d = wqkvb + 1048576; off = i - 1310720; }
        else if (i < 1835008) { s = wv; d = wqkvb + 2097152; off = i - 1572864; }
        else if (i < 2097152) { s = wo; d = wob;   off = i - 1835008; }
        else if (i < 3145728) { s = w1; d = w1b;   off = i - 2097152; }
        else                  { s = w2; d = w2b;   off = i - 3145728; }
        float4 v = reinterpret_cast<const float4*>(s)[off];
        ushort4 o;
        o.x = f2bf(v.x); o.y = f2bf(v.y); o.z = f2bf(v.z); o.w = f2bf(v.w);
        reinterpret_cast<ushort4*>(d)[off] = o;
    }
}

// bias concat (3072) + mask->mbias pre-scaled by log2(e) (4096). grid 28x256
__global__ __launch_bounds__(256) void prep_misc(const float* __restrict__ bq,
                                                 const float* __restrict__ bk,
                                                 const float* __restrict__ bv,
                                                 const int* __restrict__ mask,
                                                 float* __restrict__ bqkv,
                                                 float* __restrict__ mbias) {
    int i = blockIdx.x * 256 + threadIdx.x;
    if (i < 3 * D_) {
        float v = (i < D_) ? bq[i] : (i < 2 * D_) ? bk[i - D_] : bv[i - 2 * D_];
        bqkv[i] = v;
    } else if (i < 3 * D_ + B_ * S_) {
        int k = i - 3 * D_;
        mbias[k] = (mask[k] == 0) ? -1.44269504e9f : 0.0f;   // log2-domain
    }
}

// ---------------- 256x256 8-phase GEMM: C[M,N] = A[M,K] @ B[N,K]^T + bias ----
// EPI: 0 = bias, store bf16 ; 2 = bias + erf-GELU, store bf16
template <int EPI>
__global__ __launch_bounds__(512, 2) void gemm256_bt(const u16* __restrict__ A,
                                                     const u16* __restrict__ Bw,
                                                     const float* __restrict__ bias,
                                                     u16* __restrict__ Cb,
                                                     int N, int K) {
    __shared__ alignas(16) u16 sA[2][2][8192];   // [parity][half][128 rows x 64 k]
    __shared__ alignas(16) u16 sB[2][2][8192];
    const int tid = threadIdx.x;
    const int wid = tid >> 6, lane = tid & 63;
    const int lrow = lane & 15, lgrp = lane >> 4;
    const int wm = wid >> 2, wn = wid & 3;       // 2 x 4 wave grid

    // bijective XCD swizzle (m204)
    const int nbx = gridDim.x;
    const int nwg = nbx * gridDim.y;
    const int orig = blockIdx.y * nbx + blockIdx.x;
    const int qd = nwg >> 3, rr = nwg & 7, xc = orig & 7, oi = orig >> 3;
    const int swz = (xc < rr ? xc * (qd + 1) : rr * (qd + 1) + (xc - rr) * qd) + oi;
    const int m0 = (swz % nbx) * 256, n0 = (swz / nbx) * 256;

    const u16* Ab = A + (size_t)m0 * K;
    const u16* Bb = Bw + (size_t)n0 * K;
    const int T = K >> 6;

    const int c0 = (wid * 2 + 0) * 64 + lane;
    const int c1 = (wid * 2 + 1) * 64 + lane;
    const int r0 = c0 >> 3, g0 = c0 & 7;
    const int r1 = c1 >> 3, g1 = c1 & 7;
    const size_t so0 = (size_t)r0 * K + (size_t)((g0 ^ (r0 & 7)) * 8);
    const size_t so1 = (size_t)r1 * K + (size_t)((g1 ^ (r1 & 7)) * 8);
    const int d0 = (wid * 2 + 0) * 512;
    const int d1 = (wid * 2 + 1) * 512;

    auto stageA = [&](int par, int half, int kt) {
        const u16* src = Ab + (size_t)(half * 128) * K + kt * 64;
        g2l16(src + so0, &sA[par][half][d0]);
        g2l16(src + so1, &sA[par][half][d1]);
    };
    auto stageB = [&](int par, int half, int kt) {
        const u16* src = Bb + (size_t)(half * 128) * K + kt * 64;
        g2l16(src + so0, &sB[par][half][d0]);
        g2l16(src + so1, &sB[par][half][d1]);
    };

    stageA(0, 0, 0); stageA(0, 1, 0);
    stageB(0, 0, 0); stageB(0, 1, 0);
    if (T > 1) { stageB(1, 0, 1); stageB(1, 1, 1); }
    asm volatile("s_waitcnt vmcnt(4)" ::: "memory");
    asm volatile("s_barrier" ::: "memory");

    floatx4 acc[8][4] = {};
    const int rbase = (wn & 1) * 64;
    const int bhalf = wn >> 1;

    for (int t = 0; t < T; t++) {
        const int par = t & 1;
        const char* baseA = (const char*)&sA[par][wm][0];
        const char* baseB = (const char*)&sB[par][bhalf][0];
        short8 bfr[4][2];
#pragma unroll
        for (int ph = 0; ph < 4; ph++) {
            if (ph == 0) {
#pragma unroll
                for (int nj = 0; nj < 4; nj++) {
                    int rb = rbase + nj * 16 + lrow;
#pragma unroll
                    for (int kk = 0; kk < 2; kk++) {
                        int off = rb * 128 + (((kk * 4 + lgrp) ^ (lrow & 7)) * 16);
                        bfr[nj][kk] = *reinterpret_cast<const short8*>(baseB + off);
                    }
                }
            }
            short8 af[2][2];
#pragma unroll
            for (int a = 0; a < 2; a++) {
                int ra = (2 * ph + a) * 16 + lrow;
#pragma unroll
                for (int kk = 0; kk < 2; kk++) {
                    int off = ra * 128 + (((kk * 4 + lgrp) ^ (lrow & 7)) * 16);
                    af[a][kk] = *reinterpret_cast<const short8*>(baseA + off);
                }
            }
            if (ph == 0) { if (t + 1 < T) stageA(par ^ 1, 0, t + 1); }
            if (ph == 1) { if (t + 1 < T) stageA(par ^ 1, 1, t + 1); }
            if (ph == 2) { if (t + 2 < T) stageB(par, 0, t + 2); }
            if (ph == 3) { if (t + 2 < T) stageB(par, 1, t + 2); }

            asm volatile("s_barrier" ::: "memory");
            asm volatile("s_waitcnt lgkmcnt(0)" ::: "memory");
            __builtin_amdgcn_sched_barrier(0);

            __builtin_amdgcn_s_setprio(1);
#pragma unroll
            for (int a = 0; a < 2; a++)
#pragma unroll
                for (int nj = 0; nj < 4; nj++) {
                    acc[2 * ph + a][nj] = __builtin_amdgcn_mfma_f32_16x16x32_bf16(
                        af[a][0], bfr[nj][0], acc[2 * ph + a][nj], 0, 0, 0);
                    acc[2 * ph + a][nj] = __builtin_amdgcn_mfma_f32_16x16x32_bf16(
                        af[a][1], bfr[nj][1], acc[2 * ph + a][nj], 0, 0, 0);
                }
            __builtin_amdgcn_s_setprio(0);

            if (ph == 3) {
                if (t >= T - 3) asm volatile("s_waitcnt vmcnt(0)" ::: "memory");
                else            asm volatile("s_waitcnt vmcnt(4)" ::: "memory");
            }
            asm volatile("s_barrier" ::: "memory");
        }
    }

#pragma unroll
    for (int mi = 0; mi < 8; mi++) {
        int row = m0 + wm * 128 + mi * 16 + lgrp * 4;
#pragma unroll
        for (int nj = 0; nj < 4; nj++) {
            int col = n0 + wn * 64 + nj * 16 + lrow;
            float bc = bias[col];
#pragma unroll
            for (int j = 0; j < 4; j++) {
                float v = acc[mi][nj][j] + bc;
                if (EPI == 2) v = 0.5f * v * (1.0f + erff(v * 0.70710678118654752f));
                Cb[(size_t)(row + j) * N + col] = f2bf(v);
            }
        }
    }
}

// ---------------- split-K 128x128 GEMM -> fp32 partials ----------------------
// blockIdx.z = k-chunk; chunk z computes over K/SPLIT columns and writes its
// own partial buffer Cf + z*M_*N. Bias added by chunk 0 only. Restores TLP
// for small-N shapes (proj/FFN2): grid = 256*SPLIT blocks instead of 256.
template <int SPLIT>
__global__ __launch_bounds__(256) void gemm_sk(const u16* __restrict__ A,
                                               const u16* __restrict__ Bw,
                                               const float* __restrict__ bias,
                                               float* __restrict__ Cf,
                                               int N, int K) {
    __shared__ u16 sA[128 * 32];
    __shared__ u16 sB[128 * 32];
    const int tid = threadIdx.x;
    const int wid = tid >> 6, lane = tid & 63;
    const int lrow = lane & 15, lgrp = lane >> 4;
    const int z = blockIdx.z;
    const int Kc = K / SPLIT;

    const int nbx = gridDim.x;
    const int nwg = nbx * gridDim.y;
    const int orig = blockIdx.y * nbx + blockIdx.x;
    const int qd = nwg >> 3, rr = nwg & 7, xc = orig & 7, oi = orig >> 3;
    const int swz = (xc < rr ? xc * (qd + 1) : rr * (qd + 1) + (xc - rr) * qd) + oi;
    const int m0 = (swz % nbx) * 128, n0 = (swz / nbx) * 128;

    const int wm = wid >> 1, wn = wid & 1;
    const int ar = lane >> 2, ac = lane & 3;

    floatx4 acc[4][4] = {};
    const u16* Ab = A + (size_t)m0 * K;
    const u16* Bb = Bw + (size_t)n0 * K;
    float* Co = Cf + (size_t)z * M_ * N;

    for (int k0 = z * Kc; k0 < (z + 1) * Kc; k0 += 32) {
#pragma unroll
        for (int i = 0; i < 2; i++) {
            int seg = wid * 2 + i;
            int row = seg * 16 + ar;
            g2l16(Ab + (size_t)row * K + k0 + ac * 8, &sA[seg * 512]);
            g2l16(Bb + (size_t)row * K + k0 + ac * 8, &sB[seg * 512]);
        }
        __syncthreads();
        short8 af[4], bfr[4];
#pragma unroll
        for (int mi = 0; mi < 4; mi++)
            af[mi] = *reinterpret_cast<const short8*>(
                &sA[(wm * 64 + mi * 16 + lrow) * 32 + lgrp * 8]);
#pragma unroll
        for (int ni = 0; ni < 4; ni++)
            bfr[ni] = *reinterpret_cast<const short8*>(
                &sB[(wn * 64 + ni * 16 + lrow) * 32 + lgrp * 8]);
#pragma unroll
        for (int mi = 0; mi < 4; mi++)
#pragma unroll
            for (int ni = 0; ni < 4; ni++)
                acc[mi][ni] = __builtin_amdgcn_mfma_f32_16x16x32_bf16(
                    af[mi], bfr[ni], acc[mi][ni], 0, 0, 0);
        __syncthreads();
    }

#pragma unroll
    for (int mi = 0; mi < 4; mi++) {
        int row = m0 + wm * 64 + mi * 16 + lgrp * 4;
#pragma unroll
        for (int ni = 0; ni < 4; ni++) {
            int col = n0 + wn * 64 + ni * 16 + lrow;
            float bc = (z == 0) ? bias[col] : 0.0f;
#pragma unroll
            for (int j = 0; j < 4; j++)
                Co[(size_t)(row + j) * N + col] = acc[mi][ni][j] + bc;
        }
    }
}

// ---------------- flash attention (8 waves, swapped QK^T, exp2 softmax) -----
__global__ __launch_bounds__(512) void attn_kernel(const u16* __restrict__ QKV,
                                                   const float* __restrict__ mbias,
                                                   u16* __restrict__ O) {
    const int SD = 3 * D_;
    __shared__ alignas(16) u16 ktL[2][4096];   // [buf][64 kv][64 d] src-swizzled
    __shared__ alignas(16) u16 vtL[2][4096];   // [buf] tr-subtiled V
    __shared__ alignas(16) u16 pL[8][1024];    // per-wave P [16 q][64 kv] swizzled

    const int orig = blockIdx.y * gridDim.x + blockIdx.x;   // 512 wgs
    const int swz = (orig & 7) * 64 + (orig >> 3);
    const int qt = swz & 15, bh = swz >> 4;
    const int b = bh >> 4, h = bh & 15;

    const int tid = threadIdx.x, wid = tid >> 6, lane = tid & 63;
    const int lrow = lane & 15, lgrp = lane >> 4;

    const u16* Qp = QKV + h * DK_;
    const u16* Kp = QKV + D_ + h * DK_;
    const u16* Vp = QKV + 2 * D_ + h * DK_;
    const float* mbrow = mbias + b * S_;

    const int qr = qt * 128 + wid * 16 + lrow;
    const u16* qrow = Qp + (size_t)(b * S_ + qr) * SD;
    short8 aq0 = *reinterpret_cast<const short8*>(qrow + lgrp * 8);
    short8 aq1 = *reinterpret_cast<const short8*>(qrow + 32 + lgrp * 8);

    // staging source pointers (verified pattern, seg = wid, 1 chunk/lane/buf)
    const int q8 = wid * 64 + lane;
    const int krow = q8 >> 3, kcb = q8 & 7;
    const u16* kq = Kp + (size_t)(b * S_ + krow) * SD + ((kcb ^ (krow & 7)) * 8);
    const int ov = wid * 512 + lane * 8;
    const int vk = ((ov >> 6) & 7) * 8 + ((ov >> 9) & 1) * 4 + ((ov >> 4) & 3);
    const int vd = (ov >> 10) * 16 + (ov & 8);
    const u16* vq = Vp + (size_t)(b * S_ + vk) * SD + vd;

    auto issue = [&](int bufIdx) {
        g2l16(kq, &ktL[bufIdx][wid * 512]);
        g2l16(vq, &vtL[bufIdx][wid * 512]);
        kq += 64 * SD;
        vq += 64 * SD;
    };

    floatx4 accO[4] = {};
    float mrun = -1e30f, lrun = 0.f;
    const float SC2 = 0.18033688011112042f;    // 0.125 * log2(e)

    issue(0);
    int cur = 0;
    for (int t = 0; t < S_ / 64; t++) {
        const int kv0 = t * 64;
        if (t < S_ / 64 - 1) {
            issue(cur ^ 1);
            asm volatile("s_waitcnt vmcnt(2)" ::: "memory");
        } else {
            asm volatile("s_waitcnt vmcnt(0)" ::: "memory");
        }
        __builtin_amdgcn_s_barrier();
        asm volatile("" ::: "memory");

        const u16* ktc = ktL[cur];
        const unsigned vva = lds_off(vtL[cur]) + lane * 8;

        float4 mb[4];
#pragma unroll
        for (int ni = 0; ni < 4; ni++)
            mb[ni] = *reinterpret_cast<const float4*>(mbrow + kv0 + ni * 16 + lgrp * 4);

        // ---- swapped QK^T: S^T[kv][q] ----
        floatx4 st[4];
        __builtin_amdgcn_s_setprio(1);
#pragma unroll
        for (int ni = 0; ni < 4; ni++) {
            int row = ni * 16 + lrow;
            int off0 = (row * 128 + lgrp * 16) ^ ((lrow & 7) << 4);
            int off1 = (row * 128 + 64 + lgrp * 16) ^ ((lrow & 7) << 4);
            short8 bk0 = *reinterpret_cast<const short8*>((const char*)ktc + off0);
            short8 bk1 = *reinterpret_cast<const short8*>((const char*)ktc + off1);
            floatx4 z = {0.f, 0.f, 0.f, 0.f};
            z = __builtin_amdgcn_mfma_f32_16x16x32_bf16(bk0, aq0, z, 0, 0, 0);
            z = __builtin_amdgcn_mfma_f32_16x16x32_bf16(bk1, aq1, z, 0, 0, 0);
            st[ni] = z;
        }
        __builtin_amdgcn_s_setprio(0);

        // ---- early V tr-read issue: latency hides under softmax ----
        bf16x4 vt0[4], vt1[4], vt2[4], vt3[4];
#pragma unroll
        for (int nd = 0; nd < 4; nd++) {
            unsigned a = vva + nd * 2048;
            TRB16(vt0[nd], a, 0);
            TRB16(vt1[nd], a, 1024);
            TRB16(vt2[nd], a, 512);
            TRB16(vt3[nd], a, 1536);
        }

        // ---- softmax (log2 domain, lane-local) ----
        float pm[4][4];
#pragma unroll
        for (int ni = 0; ni < 4; ni++) {
            const float* mbp = reinterpret_cast<const float*>(&mb[ni]);
#pragma unroll
            for (int j = 0; j < 4; j++)
                pm[ni][j] = fmaf(st[ni][j], SC2, mbp[j]);
        }
        float pmax = pm[0][0];
#pragma unroll
        for (int ni = 0; ni < 4; ni++)
#pragma unroll
            for (int j = 0; j < 4; j++) pmax = fmaxf(pmax, pm[ni][j]);
        pmax = fmaxf(pmax, __shfl_xor(pmax, 16, 64));
        pmax = fmaxf(pmax, __shfl_xor(pmax, 32, 64));

        bool upd = !__all(pmax - mrun <= 11.5f);
        float fac = 1.0f;
        if (upd) {
            float mn = fmaxf(mrun, pmax);
            fac = exp2_fast(mrun - mn);
            mrun = mn;
        }

        float p[4][4];
        float s = 0.f;
#pragma unroll
        for (int ni = 0; ni < 4; ni++)
#pragma unroll
            for (int j = 0; j < 4; j++) {
                float e = exp2_fast(pm[ni][j] - mrun);
                p[ni][j] = e;
                s += e;
            }
        s += __shfl_xor(s, 16, 64);
        s += __shfl_xor(s, 32, 64);
        lrun = lrun * fac + s;

        // ---- P -> LDS [q=lrow][kv] XOR-swizzled ----
#pragma unroll
        for (int ni = 0; ni < 4; ni++) {
            bf16x4 pw;
#pragma unroll
            for (int j = 0; j < 4; j++) pw[j] = (short)f2bf_fast(p[ni][j]);
            unsigned woff = (unsigned)((lrow * 128 + ni * 32 + lgrp * 8) ^ ((lrow & 7) << 4));
            *reinterpret_cast<bf16x4*>((char*)pL[wid] + woff) = pw;
        }

        if (upd) {
            float f0 = __shfl(fac, lgrp * 4 + 0, 64);
            float f1 = __shfl(fac, lgrp * 4 + 1, 64);
            float f2 = __shfl(fac, lgrp * 4 + 2, 64);
            float f3 = __shfl(fac, lgrp * 4 + 3, 64);
#pragma unroll
            for (int nd = 0; nd < 4; nd++) {
                floatx4 tt = accO[nd];
                tt[0] *= f0; tt[1] *= f1; tt[2] *= f2; tt[3] *= f3;
                accO[nd] = tt;
            }
        }

        asm volatile("s_waitcnt lgkmcnt(0)" ::: "memory");
        __builtin_amdgcn_sched_barrier(0);

        // P A-frags (plain reads; compiler inserts its own waits)
        unsigned ra0 = (unsigned)((lrow * 128 + lgrp * 16) ^ ((lrow & 7) << 4));
        unsigned ra1 = (unsigned)((lrow * 128 + 64 + lgrp * 16) ^ ((lrow & 7) << 4));
        short8 ap0 = *reinterpret_cast<const short8*>((const char*)pL[wid] + ra0);
        short8 ap1 = *reinterpret_cast<const short8*>((const char*)pL[wid] + ra1);

        __builtin_amdgcn_s_setprio(1);
#pragma unroll
        for (int nd = 0; nd < 4; nd++) {
            short8 bv0 = __builtin_shufflevector(vt0[nd], vt1[nd], 0, 1, 2, 3, 4, 5, 6, 7);
            short8 bv1 = __builtin_shufflevector(vt2[nd], vt3[nd], 0, 1, 2, 3, 4, 5, 6, 7);
            accO[nd] = __builtin_amdgcn_mfma_f32_16x16x32_bf16(ap0, bv0, accO[nd], 0, 0, 0);
            accO[nd] = __builtin_amdgcn_mfma_f32_16x16x32_bf16(ap1, bv1, accO[nd], 0, 0, 0);
        }
        __builtin_amdgcn_s_setprio(0);

        asm volatile("" ::: "memory");
        __builtin_amdgcn_s_barrier();
        cur ^= 1;
    }

    float linv = 1.0f / lrun;
    float li[4];
#pragma unroll
    for (int j = 0; j < 4; j++) li[j] = __shfl(linv, lgrp * 4 + j, 64);
#pragma unroll
    for (int nd = 0; nd < 4; nd++)
#pragma unroll
        for (int j = 0; j < 4; j++) {
            int r = lgrp * 4 + j;
            float v = accO[nd][j] * li[j];
            O[(size_t)(b * S_ + qt * 128 + wid * 16 + r) * D_ + h * DK_ + nd * 16 + lrow] =
                f2bf_fast(v);
        }
}

// ---------------- residual(+split-K partials) + LayerNorm --------------------
// torch semantics: ddof=1, eps OUTSIDE sqrt. v = X + R0 [+R1 +R2 +R3]
template <int NR>
__global__ __launch_bounds__(256) void ln_kernel(const float* __restrict__ X,
                                                 const float* __restrict__ R0,
                                                 const float* __restrict__ R1,
                                                 const float* __restrict__ R2,
                                                 const float* __restrict__ R3,
                                                 const float* __restrict__ gam,
                                                 const float* __restrict__ bet,
                                                 float* __restrict__ outf,
                                                 u16* __restrict__ outb) {
    __shared__ float ws1[4], ws2[4];
    const int row = blockIdx.x, tid = threadIdx.x;
    const size_t ro = (size_t)row * D_;
    float4 v = reinterpret_cast<const float4*>(X + ro)[tid];
    {
        const float4 r = reinterpret_cast<const float4*>(R0 + ro)[tid];
        v.x += r.x; v.y += r.y; v.z += r.z; v.w += r.w;
    }
    if (NR >= 2) {
        const float4 r = reinterpret_cast<const float4*>(R1 + ro)[tid];
        v.x += r.x; v.y += r.y; v.z += r.z; v.w += r.w;
    }
    if (NR >= 3) {
        const float4 r = reinterpret_cast<const float4*>(R2 + ro)[tid];
        v.x += r.x; v.y += r.y; v.z += r.z; v.w += r.w;
    }
    if (NR >= 4) {
        const float4 r = reinterpret_cast<const float4*>(R3 + ro)[tid];
        v.x += r.x; v.y += r.y; v.z += r.z; v.w += r.w;
    }

    float s = v.x + v.y + v.z + v.w;
#pragma unroll
    for (int m = 32; m >= 1; m >>= 1) s += __shfl_xor(s, m, 64);
    if ((tid & 63) == 0) ws1[tid >> 6] = s;
    __syncthreads();
    float mean = (ws1[0] + ws1[1] + ws1[2] + ws1[3]) * (1.f / D_);

    float4 d; d.x = v.x - mean; d.y = v.y - mean; d.z = v.z - mean; d.w = v.w - mean;
    float q = d.x * d.x + d.y * d.y + d.z * d.z + d.w * d.w;
#pragma unroll
    for (int m = 32; m >= 1; m >>= 1) q += __shfl_xor(q, m, 64);
    if ((tid & 63) == 0) ws2[tid >> 6] = q;
    __syncthreads();
    float var = (ws2[0] + ws2[1] + ws2[2] + ws2[3]) * (1.f / (D_ - 1));
    float inv = 1.f / (sqrtf(var) + 1e-6f);

    const float4 g = reinterpret_cast<const float4*>(gam)[tid];
    const float4 bb = reinterpret_cast<const float4*>(bet)[tid];
    float4 o;
    o.x = g.x * d.x * inv + bb.x;
    o.y = g.y * d.y * inv + bb.y;
    o.z = g.z * d.z * inv + bb.z;
    o.w = g.w * d.w * inv + bb.w;
    if (outf) reinterpret_cast<float4*>(outf + ro)[tid] = o;
    if (outb) {
        ushort4 ob;
        ob.x = f2bf(o.x); ob.y = f2bf(o.y); ob.z = f2bf(o.z); ob.w = f2bf(o.w);
        reinterpret_cast<ushort4*>(outb + ro)[tid] = ob;
    }
}

// ---------------- launcher ----------------
extern "C" void kernel_launch(void* const* d_in, const int* in_sizes, int n_in,
                              void* d_out, int out_size, void* d_ws, size_t ws_size,
                              hipStream_t stream) {
    const float* x    = (const float*)d_in[0];
    const int*   mask = (const int*)d_in[1];
    const float* wq   = (const float*)d_in[2];
    const float* bq   = (const float*)d_in[3];
    const float* wk   = (const float*)d_in[4];
    const float* bk   = (const float*)d_in[5];
    const float* wv   = (const float*)d_in[6];
    const float* bv   = (const float*)d_in[7];
    const float* wo   = (const float*)d_in[8];
    const float* bo   = (const float*)d_in[9];
    const float* g1   = (const float*)d_in[10];
    const float* b1   = (const float*)d_in[11];
    const float* g2   = (const float*)d_in[12];
    const float* b2   = (const float*)d_in[13];
    const float* w1   = (const float*)d_in[14];
    const float* bf1  = (const float*)d_in[15];
    const float* w2   = (const float*)d_in[16];
    const float* bf2  = (const float*)d_in[17];
    float* out = (float*)d_out;

    char* ws = (char*)d_ws;
    const size_t MB = 1u << 20;
    // Region A (0..78 MB): lifetime ends at LN1. FFN2 partials alias it.
    u16*   xb    = (u16*)  (ws + 0 * MB);    // 8 MB   (dead after QKV)
    u16*   wqkvb = (u16*)  (ws + 8 * MB);    // 6 MB   (dead after QKV)
    u16*   qkvb  = (u16*)  (ws + 14 * MB);   // 24 MB  (dead after attn)
    u16*   cvb   = (u16*)  (ws + 38 * MB);   // 8 MB   (dead after proj)
    float* p0    = (float*)(ws + 46 * MB);   // 16 MB  (dead after LN1)
    float* p1    = (float*)(ws + 62 * MB);   // 16 MB  (dead after LN1)
    float* qpart = (float*)(ws + 0 * MB);    // 64 MB: FFN2 partials, alias 0..64
    // Region B (78..153 MB): persistent across the call.
    u16*   wob   = (u16*)  (ws + 78 * MB);   // 2 MB
    u16*   w1b   = (u16*)  (ws + 80 * MB);   // 8 MB
    u16*   w2b   = (u16*)  (ws + 88 * MB);   // 8 MB
    float* bqkv  = (float*)(ws + 96 * MB);   // 12 KB
    float* mbias = (float*)(ws + 96 * MB + 65536);  // 16 KB
    float* hdf   = (float*)(ws + 97 * MB);   // 16 MB
    u16*   hdb   = (u16*)  (ws + 113 * MB);  // 8 MB
    u16*   ff1b  = (u16*)  (ws + 121 * MB);  // 32 MB -> ends 153 MB

    cvt_all<<<2048, 256, 0, stream>>>(x, wq, wk, wv, wo, w1, w2,
                                      xb, wqkvb, wob, w1b, w2b);
    prep_misc<<<28, 256, 0, stream>>>(bq, bk, bv, mask, bqkv, mbias);

    // fused QKV projection: [4096,3072,1024] on 256x256 8-phase
    gemm256_bt<0><<<dim3(M_ / 256, 3 * D_ / 256), 512, 0, stream>>>(
        xb, wqkvb, bqkv, qkvb, 3 * D_, D_);

    // attention: 8 waves, 128 q-rows per block
    attn_kernel<<<dim3(S_ / 128, B_ * H_), 512, 0, stream>>>(qkvb, mbias, cvb);

    // output projection: [4096,1024,1024], split-K 2 -> p0,p1
    gemm_sk<2><<<dim3(M_ / 128, D_ / 128, 2), 256, 0, stream>>>(
        cvb, wob, bo, p0, D_, D_);

    // residual + LN1: hd = LN(x + p0 + p1)
    ln_kernel<2><<<M_, 256, 0, stream>>>(x, p0, p1, nullptr, nullptr,
                                         g1, b1, hdf, hdb);

    // FFN1 + GELU: [4096,4096,1024] on 256x256 8-phase
    gemm256_bt<2><<<dim3(M_ / 256, DFF_ / 256), 512, 0, stream>>>(
        hdb, w1b, bf1, ff1b, DFF_, D_);

    // FFN2: [4096,1024,4096], split-K 4 -> qpart[0..3]
    gemm_sk<4><<<dim3(M_ / 128, D_ / 128, 4), 256, 0, stream>>>(
        ff1b, w2b, bf2, qpart, D_, DFF_);

    // residual + LN2 -> out = LN(hdf + q0 + q1 + q2 + q3)
    ln_kernel<4><<<M_, 256, 0, stream>>>(hdf, qpart, qpart + (size_t)M_ * D_,
                                         qpart + 2 * (size_t)M_ * D_,
                                         qpart + 3 * (size_t)M_ * D_,
                                         g2, b2, out, nullptr);
}

// Round 9
// 381.561 us; speedup vs baseline: 1.4717x; 1.0761x over previous
//
#include <hip/hip_runtime.h>
#include <hip/hip_bf16.h>

// ---------------- constants (problem shape) ----------------
#define B_   2
#define S_   2048
#define D_   1024
#define H_   16
#define DK_  64
#define DFF_ 4096
#define M_   (B_*S_)   // 4096 rows

typedef unsigned short u16;
typedef __attribute__((ext_vector_type(8))) short short8;
typedef __attribute__((ext_vector_type(4))) short bf16x4;
typedef __attribute__((ext_vector_type(4))) float floatx4;

__device__ __forceinline__ u16 f2bf(float f) {
    union { float f; unsigned u; } v; v.f = f;
    unsigned r = v.u + 0x7fffu + ((v.u >> 16) & 1u);
    return (u16)(r >> 16);
}
__device__ __forceinline__ u16 f2bf_fast(float f) {
    __hip_bfloat16 h = __float2bfloat16(f);
    return *reinterpret_cast<u16*>(&h);
}
__device__ __forceinline__ float exp2_fast(float f) {
    return __builtin_amdgcn_exp2f(f);
}
__device__ __forceinline__ void g2l16(const u16* g, u16* l) {
    __builtin_amdgcn_global_load_lds((const __attribute__((address_space(1))) void*)g,
                                     (__attribute__((address_space(3))) void*)l,
                                     16, 0, 0);
}
__device__ __forceinline__ unsigned lds_off(const void* p) {
    return (unsigned)(unsigned long long)p;
}

#define TRB16(dst, va, IMM)                                                    \
    asm volatile("ds_read_b64_tr_b16 %0, %1 offset:" #IMM                      \
                 : "=v"(dst) : "v"(va))

// ---------------- fused fp32->bf16 conversion of x + all weights ----------------
__global__ __launch_bounds__(256) void cvt_all(
    const float* __restrict__ x,  const float* __restrict__ wq,
    const float* __restrict__ wk, const float* __restrict__ wv,
    const float* __restrict__ wo, const float* __restrict__ w1,
    const float* __restrict__ w2,
    u16* __restrict__ xb, u16* __restrict__ wqkvb, u16* __restrict__ wob,
    u16* __restrict__ w1b, u16* __restrict__ w2b) {
    for (int i = blockIdx.x * 256 + threadIdx.x; i < 4194304;
         i += gridDim.x * 256) {
        const float* s; u16* d; int off;
        if (i < 1048576)      { s = x;  d = xb;    off = i; }
        else if (i < 1310720) { s = wq; d = wqkvb; off = i - 1048576; }
        else if (i < 1572864) { s = wk; d = wqkvb + 1048576; off = i - 1310720; }
        else if (i < 1835008) { s = wv; d = wqkvb + 2097152; off = i - 1572864; }
        else if (i < 2097152) { s = wo; d = wob;   off = i - 1835008; }
        else if (i < 3145728) { s = w1; d = w1b;   off = i - 2097152; }
        else                  { s = w2; d = w2b;   off = i - 3145728; }
        float4 v = reinterpret_cast<const float4*>(s)[off];
        ushort4 o;
        o.x = f2bf(v.x); o.y = f2bf(v.y); o.z = f2bf(v.z); o.w = f2bf(v.w);
        reinterpret_cast<ushort4*>(d)[off] = o;
    }
}

// bias concat (3072) + mask->mbias pre-scaled by log2(e) (4096). grid 28x256
__global__ __launch_bounds__(256) void prep_misc(const float* __restrict__ bq,
                                                 const float* __restrict__ bk,
                                                 const float* __restrict__ bv,
                                                 const int* __restrict__ mask,
                                                 float* __restrict__ bqkv,
                                                 float* __restrict__ mbias) {
    int i = blockIdx.x * 256 + threadIdx.x;
    if (i < 3 * D_) {
        float v = (i < D_) ? bq[i] : (i < 2 * D_) ? bk[i - D_] : bv[i - 2 * D_];
        bqkv[i] = v;
    } else if (i < 3 * D_ + B_ * S_) {
        int k = i - 3 * D_;
        mbias[k] = (mask[k] == 0) ? -1.44269504e9f : 0.0f;   // log2-domain
    }
}

// ---------------- 256x256 8-phase GEMM with optional split-K -----------------
// C[M,N] = A[M,K_chunk] @ B[N,K_chunk]^T (+ bias at z==0)
// blockIdx.z = K-chunk; Kc = K / gridDim.z. n-fastest tile mapping: co-XCD
// chunks share A-panels (A fetched ~once). EPI: 0 = bias->bf16;
// 1 = fp32 partial (z-offset buffer, bias z==0); 2 = bias+erf-GELU->bf16.
template <int EPI>
__global__ __launch_bounds__(512, 2) void gemm256_bt(const u16* __restrict__ A,
                                                     const u16* __restrict__ Bw,
                                                     const float* __restrict__ bias,
                                                     u16* __restrict__ Cb,
                                                     float* __restrict__ Cf,
                                                     int N, int K) {
    __shared__ alignas(16) u16 sA[2][2][8192];   // [parity][half][128 rows x 64 k]
    __shared__ alignas(16) u16 sB[2][2][8192];
    const int tid = threadIdx.x;
    const int wid = tid >> 6, lane = tid & 63;
    const int lrow = lane & 15, lgrp = lane >> 4;
    const int wm = wid >> 2, wn = wid & 3;       // 2 x 4 wave grid
    const int z = blockIdx.z;
    const int Kc = K / gridDim.z;
    const int zbase = z * Kc;

    // bijective XCD swizzle (m204), then n-fastest: chunk shares A-panels
    const int nbx = gridDim.x, nby = gridDim.y;
    const int nwg = nbx * nby;
    const int orig = blockIdx.y * nbx + blockIdx.x;
    const int qd = nwg >> 3, rr = nwg & 7, xc = orig & 7, oi = orig >> 3;
    const int swz = (xc < rr ? xc * (qd + 1) : rr * (qd + 1) + (xc - rr) * qd) + oi;
    const int m0 = (swz / nby) * 256, n0 = (swz % nby) * 256;

    const u16* Ab = A + (size_t)m0 * K + zbase;
    const u16* Bb = Bw + (size_t)n0 * K + zbase;
    const int T = Kc >> 6;

    const int c0 = (wid * 2 + 0) * 64 + lane;
    const int c1 = (wid * 2 + 1) * 64 + lane;
    const int r0 = c0 >> 3, g0 = c0 & 7;
    const int r1 = c1 >> 3, g1 = c1 & 7;
    const size_t so0 = (size_t)r0 * K + (size_t)((g0 ^ (r0 & 7)) * 8);
    const size_t so1 = (size_t)r1 * K + (size_t)((g1 ^ (r1 & 7)) * 8);
    const int d0 = (wid * 2 + 0) * 512;
    const int d1 = (wid * 2 + 1) * 512;

    auto stageA = [&](int par, int half, int kt) {
        const u16* src = Ab + (size_t)(half * 128) * K + kt * 64;
        g2l16(src + so0, &sA[par][half][d0]);
        g2l16(src + so1, &sA[par][half][d1]);
    };
    auto stageB = [&](int par, int half, int kt) {
        const u16* src = Bb + (size_t)(half * 128) * K + kt * 64;
        g2l16(src + so0, &sB[par][half][d0]);
        g2l16(src + so1, &sB[par][half][d1]);
    };

    stageA(0, 0, 0); stageA(0, 1, 0);
    stageB(0, 0, 0); stageB(0, 1, 0);
    if (T > 1) { stageB(1, 0, 1); stageB(1, 1, 1); }
    asm volatile("s_waitcnt vmcnt(4)" ::: "memory");
    asm volatile("s_barrier" ::: "memory");

    floatx4 acc[8][4] = {};
    const int rbase = (wn & 1) * 64;
    const int bhalf = wn >> 1;

    for (int t = 0; t < T; t++) {
        const int par = t & 1;
        const char* baseA = (const char*)&sA[par][wm][0];
        const char* baseB = (const char*)&sB[par][bhalf][0];
        short8 bfr[4][2];
#pragma unroll
        for (int ph = 0; ph < 4; ph++) {
            if (ph == 0) {
#pragma unroll
                for (int nj = 0; nj < 4; nj++) {
                    int rb = rbase + nj * 16 + lrow;
#pragma unroll
                    for (int kk = 0; kk < 2; kk++) {
                        int off = rb * 128 + (((kk * 4 + lgrp) ^ (lrow & 7)) * 16);
                        bfr[nj][kk] = *reinterpret_cast<const short8*>(baseB + off);
                    }
                }
            }
            short8 af[2][2];
#pragma unroll
            for (int a = 0; a < 2; a++) {
                int ra = (2 * ph + a) * 16 + lrow;
#pragma unroll
                for (int kk = 0; kk < 2; kk++) {
                    int off = ra * 128 + (((kk * 4 + lgrp) ^ (lrow & 7)) * 16);
                    af[a][kk] = *reinterpret_cast<const short8*>(baseA + off);
                }
            }
            if (ph == 0) { if (t + 1 < T) stageA(par ^ 1, 0, t + 1); }
            if (ph == 1) { if (t + 1 < T) stageA(par ^ 1, 1, t + 1); }
            if (ph == 2) { if (t + 2 < T) stageB(par, 0, t + 2); }
            if (ph == 3) { if (t + 2 < T) stageB(par, 1, t + 2); }

            asm volatile("s_barrier" ::: "memory");
            asm volatile("s_waitcnt lgkmcnt(0)" ::: "memory");
            __builtin_amdgcn_sched_barrier(0);

            __builtin_amdgcn_s_setprio(1);
#pragma unroll
            for (int a = 0; a < 2; a++)
#pragma unroll
                for (int nj = 0; nj < 4; nj++) {
                    acc[2 * ph + a][nj] = __builtin_amdgcn_mfma_f32_16x16x32_bf16(
                        af[a][0], bfr[nj][0], acc[2 * ph + a][nj], 0, 0, 0);
                    acc[2 * ph + a][nj] = __builtin_amdgcn_mfma_f32_16x16x32_bf16(
                        af[a][1], bfr[nj][1], acc[2 * ph + a][nj], 0, 0, 0);
                }
            __builtin_amdgcn_s_setprio(0);

            if (ph == 3) {
                if (t >= T - 3) asm volatile("s_waitcnt vmcnt(0)" ::: "memory");
                else            asm volatile("s_waitcnt vmcnt(4)" ::: "memory");
            }
            asm volatile("s_barrier" ::: "memory");
        }
    }

    float* Co = (EPI == 1) ? Cf + (size_t)z * M_ * N : nullptr;
#pragma unroll
    for (int mi = 0; mi < 8; mi++) {
        int row = m0 + wm * 128 + mi * 16 + lgrp * 4;
#pragma unroll
        for (int nj = 0; nj < 4; nj++) {
            int col = n0 + wn * 64 + nj * 16 + lrow;
            float bc = (EPI != 1 || z == 0) ? bias[col] : 0.0f;
#pragma unroll
            for (int j = 0; j < 4; j++) {
                float v = acc[mi][nj][j] + bc;
                if (EPI == 2) v = 0.5f * v * (1.0f + erff(v * 0.70710678118654752f));
                if (EPI == 1)
                    Co[(size_t)(row + j) * N + col] = v;
                else
                    Cb[(size_t)(row + j) * N + col] = f2bf(v);
            }
        }
    }
}

// ---------------- flash attention (8 waves, swapped QK^T, exp2 softmax) -----
__global__ __launch_bounds__(512) void attn_kernel(const u16* __restrict__ QKV,
                                                   const float* __restrict__ mbias,
                                                   u16* __restrict__ O) {
    const int SD = 3 * D_;
    __shared__ alignas(16) u16 ktL[2][4096];   // [buf][64 kv][64 d] src-swizzled
    __shared__ alignas(16) u16 vtL[2][4096];   // [buf] tr-subtiled V
    __shared__ alignas(16) u16 pL[8][1024];    // per-wave P [16 q][64 kv] swizzled

    const int orig = blockIdx.y * gridDim.x + blockIdx.x;   // 512 wgs
    const int swz = (orig & 7) * 64 + (orig >> 3);
    const int qt = swz & 15, bh = swz >> 4;
    const int b = bh >> 4, h = bh & 15;

    const int tid = threadIdx.x, wid = tid >> 6, lane = tid & 63;
    const int lrow = lane & 15, lgrp = lane >> 4;

    const u16* Qp = QKV + h * DK_;
    const u16* Kp = QKV + D_ + h * DK_;
    const u16* Vp = QKV + 2 * D_ + h * DK_;
    const float* mbrow = mbias + b * S_;

    const int qr = qt * 128 + wid * 16 + lrow;
    const u16* qrow = Qp + (size_t)(b * S_ + qr) * SD;
    short8 aq0 = *reinterpret_cast<const short8*>(qrow + lgrp * 8);
    short8 aq1 = *reinterpret_cast<const short8*>(qrow + 32 + lgrp * 8);

    const int q8 = wid * 64 + lane;
    const int krow = q8 >> 3, kcb = q8 & 7;
    const u16* kq = Kp + (size_t)(b * S_ + krow) * SD + ((kcb ^ (krow & 7)) * 8);
    const int ov = wid * 512 + lane * 8;
    const int vk = ((ov >> 6) & 7) * 8 + ((ov >> 9) & 1) * 4 + ((ov >> 4) & 3);
    const int vd = (ov >> 10) * 16 + (ov & 8);
    const u16* vq = Vp + (size_t)(b * S_ + vk) * SD + vd;

    auto issue = [&](int bufIdx) {
        g2l16(kq, &ktL[bufIdx][wid * 512]);
        g2l16(vq, &vtL[bufIdx][wid * 512]);
        kq += 64 * SD;
        vq += 64 * SD;
    };

    floatx4 accO[4] = {};
    float mrun = -1e30f, lrun = 0.f;
    const float SC2 = 0.18033688011112042f;    // 0.125 * log2(e)

    issue(0);
    int cur = 0;
    for (int t = 0; t < S_ / 64; t++) {
        const int kv0 = t * 64;
        if (t < S_ / 64 - 1) {
            issue(cur ^ 1);
            asm volatile("s_waitcnt vmcnt(2)" ::: "memory");
        } else {
            asm volatile("s_waitcnt vmcnt(0)" ::: "memory");
        }
        __builtin_amdgcn_s_barrier();
        asm volatile("" ::: "memory");

        const u16* ktc = ktL[cur];
        const unsigned vva = lds_off(vtL[cur]) + lane * 8;

        float4 mb[4];
#pragma unroll
        for (int ni = 0; ni < 4; ni++)
            mb[ni] = *reinterpret_cast<const float4*>(mbrow + kv0 + ni * 16 + lgrp * 4);

        // ---- swapped QK^T: S^T[kv][q] ----
        floatx4 st[4];
        __builtin_amdgcn_s_setprio(1);
#pragma unroll
        for (int ni = 0; ni < 4; ni++) {
            int row = ni * 16 + lrow;
            int off0 = (row * 128 + lgrp * 16) ^ ((lrow & 7) << 4);
            int off1 = (row * 128 + 64 + lgrp * 16) ^ ((lrow & 7) << 4);
            short8 bk0 = *reinterpret_cast<const short8*>((const char*)ktc + off0);
            short8 bk1 = *reinterpret_cast<const short8*>((const char*)ktc + off1);
            floatx4 z = {0.f, 0.f, 0.f, 0.f};
            z = __builtin_amdgcn_mfma_f32_16x16x32_bf16(bk0, aq0, z, 0, 0, 0);
            z = __builtin_amdgcn_mfma_f32_16x16x32_bf16(bk1, aq1, z, 0, 0, 0);
            st[ni] = z;
        }
        __builtin_amdgcn_s_setprio(0);

        // ---- early V tr-read issue: latency hides under softmax ----
        bf16x4 vt0[4], vt1[4], vt2[4], vt3[4];
#pragma unroll
        for (int nd = 0; nd < 4; nd++) {
            unsigned a = vva + nd * 2048;
            TRB16(vt0[nd], a, 0);
            TRB16(vt1[nd], a, 1024);
            TRB16(vt2[nd], a, 512);
            TRB16(vt3[nd], a, 1536);
        }

        // ---- softmax (log2 domain, lane-local) ----
        float pm[4][4];
#pragma unroll
        for (int ni = 0; ni < 4; ni++) {
            const float* mbp = reinterpret_cast<const float*>(&mb[ni]);
#pragma unroll
            for (int j = 0; j < 4; j++)
                pm[ni][j] = fmaf(st[ni][j], SC2, mbp[j]);
        }
        float pmax = pm[0][0];
#pragma unroll
        for (int ni = 0; ni < 4; ni++)
#pragma unroll
            for (int j = 0; j < 4; j++) pmax = fmaxf(pmax, pm[ni][j]);
        pmax = fmaxf(pmax, __shfl_xor(pmax, 16, 64));
        pmax = fmaxf(pmax, __shfl_xor(pmax, 32, 64));

        bool upd = !__all(pmax - mrun <= 11.5f);
        float fac = 1.0f;
        if (upd) {
            float mn = fmaxf(mrun, pmax);
            fac = exp2_fast(mrun - mn);
            mrun = mn;
        }

        float p[4][4];
        float s = 0.f;
#pragma unroll
        for (int ni = 0; ni < 4; ni++)
#pragma unroll
            for (int j = 0; j < 4; j++) {
                float e = exp2_fast(pm[ni][j] - mrun);
                p[ni][j] = e;
                s += e;
            }
        s += __shfl_xor(s, 16, 64);
        s += __shfl_xor(s, 32, 64);
        lrun = lrun * fac + s;

        // ---- P -> LDS [q=lrow][kv] XOR-swizzled ----
#pragma unroll
        for (int ni = 0; ni < 4; ni++) {
            bf16x4 pw;
#pragma unroll
            for (int j = 0; j < 4; j++) pw[j] = (short)f2bf_fast(p[ni][j]);
            unsigned woff = (unsigned)((lrow * 128 + ni * 32 + lgrp * 8) ^ ((lrow & 7) << 4));
            *reinterpret_cast<bf16x4*>((char*)pL[wid] + woff) = pw;
        }

        if (upd) {
            float f0 = __shfl(fac, lgrp * 4 + 0, 64);
            float f1 = __shfl(fac, lgrp * 4 + 1, 64);
            float f2 = __shfl(fac, lgrp * 4 + 2, 64);
            float f3 = __shfl(fac, lgrp * 4 + 3, 64);
#pragma unroll
            for (int nd = 0; nd < 4; nd++) {
                floatx4 tt = accO[nd];
                tt[0] *= f0; tt[1] *= f1; tt[2] *= f2; tt[3] *= f3;
                accO[nd] = tt;
            }
        }

        asm volatile("s_waitcnt lgkmcnt(0)" ::: "memory");
        __builtin_amdgcn_sched_barrier(0);

        unsigned ra0 = (unsigned)((lrow * 128 + lgrp * 16) ^ ((lrow & 7) << 4));
        unsigned ra1 = (unsigned)((lrow * 128 + 64 + lgrp * 16) ^ ((lrow & 7) << 4));
        short8 ap0 = *reinterpret_cast<const short8*>((const char*)pL[wid] + ra0);
        short8 ap1 = *reinterpret_cast<const short8*>((const char*)pL[wid] + ra1);

        __builtin_amdgcn_s_setprio(1);
#pragma unroll
        for (int nd = 0; nd < 4; nd++) {
            short8 bv0 = __builtin_shufflevector(vt0[nd], vt1[nd], 0, 1, 2, 3, 4, 5, 6, 7);
            short8 bv1 = __builtin_shufflevector(vt2[nd], vt3[nd], 0, 1, 2, 3, 4, 5, 6, 7);
            accO[nd] = __builtin_amdgcn_mfma_f32_16x16x32_bf16(ap0, bv0, accO[nd], 0, 0, 0);
            accO[nd] = __builtin_amdgcn_mfma_f32_16x16x32_bf16(ap1, bv1, accO[nd], 0, 0, 0);
        }
        __builtin_amdgcn_s_setprio(0);

        asm volatile("" ::: "memory");
        __builtin_amdgcn_s_barrier();
        cur ^= 1;
    }

    float linv = 1.0f / lrun;
    float li[4];
#pragma unroll
    for (int j = 0; j < 4; j++) li[j] = __shfl(linv, lgrp * 4 + j, 64);
#pragma unroll
    for (int nd = 0; nd < 4; nd++)
#pragma unroll
        for (int j = 0; j < 4; j++) {
            int r = lgrp * 4 + j;
            float v = accO[nd][j] * li[j];
            O[(size_t)(b * S_ + qt * 128 + wid * 16 + r) * D_ + h * DK_ + nd * 16 + lrow] =
                f2bf_fast(v);
        }
}

// ---------------- residual(+split-K partials) + LayerNorm --------------------
// torch semantics: ddof=1, eps OUTSIDE sqrt. v = X + R0 [+R1 +R2 +R3]
template <int NR>
__global__ __launch_bounds__(256) void ln_kernel(const float* __restrict__ X,
                                                 const float* __restrict__ R0,
                                                 const float* __restrict__ R1,
                                                 const float* __restrict__ R2,
                                                 const float* __restrict__ R3,
                                                 const float* __restrict__ gam,
                                                 const float* __restrict__ bet,
                                                 float* __restrict__ outf,
                                                 u16* __restrict__ outb) {
    __shared__ float ws1[4], ws2[4];
    const int row = blockIdx.x, tid = threadIdx.x;
    const size_t ro = (size_t)row * D_;
    float4 v = reinterpret_cast<const float4*>(X + ro)[tid];
    {
        const float4 r = reinterpret_cast<const float4*>(R0 + ro)[tid];
        v.x += r.x; v.y += r.y; v.z += r.z; v.w += r.w;
    }
    if (NR >= 2) {
        const float4 r = reinterpret_cast<const float4*>(R1 + ro)[tid];
        v.x += r.x; v.y += r.y; v.z += r.z; v.w += r.w;
    }
    if (NR >= 3) {
        const float4 r = reinterpret_cast<const float4*>(R2 + ro)[tid];
        v.x += r.x; v.y += r.y; v.z += r.z; v.w += r.w;
    }
    if (NR >= 4) {
        const float4 r = reinterpret_cast<const float4*>(R3 + ro)[tid];
        v.x += r.x; v.y += r.y; v.z += r.z; v.w += r.w;
    }

    float s = v.x + v.y + v.z + v.w;
#pragma unroll
    for (int m = 32; m >= 1; m >>= 1) s += __shfl_xor(s, m, 64);
    if ((tid & 63) == 0) ws1[tid >> 6] = s;
    __syncthreads();
    float mean = (ws1[0] + ws1[1] + ws1[2] + ws1[3]) * (1.f / D_);

    float4 d; d.x = v.x - mean; d.y = v.y - mean; d.z = v.z - mean; d.w = v.w - mean;
    float q = d.x * d.x + d.y * d.y + d.z * d.z + d.w * d.w;
#pragma unroll
    for (int m = 32; m >= 1; m >>= 1) q += __shfl_xor(q, m, 64);
    if ((tid & 63) == 0) ws2[tid >> 6] = q;
    __syncthreads();
    float var = (ws2[0] + ws2[1] + ws2[2] + ws2[3]) * (1.f / (D_ - 1));
    float inv = 1.f / (sqrtf(var) + 1e-6f);

    const float4 g = reinterpret_cast<const float4*>(gam)[tid];
    const float4 bb = reinterpret_cast<const float4*>(bet)[tid];
    float4 o;
    o.x = g.x * d.x * inv + bb.x;
    o.y = g.y * d.y * inv + bb.y;
    o.z = g.z * d.z * inv + bb.z;
    o.w = g.w * d.w * inv + bb.w;
    if (outf) reinterpret_cast<float4*>(outf + ro)[tid] = o;
    if (outb) {
        ushort4 ob;
        ob.x = f2bf(o.x); ob.y = f2bf(o.y); ob.z = f2bf(o.z); ob.w = f2bf(o.w);
        reinterpret_cast<ushort4*>(outb + ro)[tid] = ob;
    }
}

// ---------------- launcher ----------------
extern "C" void kernel_launch(void* const* d_in, const int* in_sizes, int n_in,
                              void* d_out, int out_size, void* d_ws, size_t ws_size,
                              hipStream_t stream) {
    const float* x    = (const float*)d_in[0];
    const int*   mask = (const int*)d_in[1];
    const float* wq   = (const float*)d_in[2];
    const float* bq   = (const float*)d_in[3];
    const float* wk   = (const float*)d_in[4];
    const float* bk   = (const float*)d_in[5];
    const float* wv   = (const float*)d_in[6];
    const float* bv   = (const float*)d_in[7];
    const float* wo   = (const float*)d_in[8];
    const float* bo   = (const float*)d_in[9];
    const float* g1   = (const float*)d_in[10];
    const float* b1   = (const float*)d_in[11];
    const float* g2   = (const float*)d_in[12];
    const float* b2   = (const float*)d_in[13];
    const float* w1   = (const float*)d_in[14];
    const float* bf1  = (const float*)d_in[15];
    const float* w2   = (const float*)d_in[16];
    const float* bf2  = (const float*)d_in[17];
    float* out = (float*)d_out;

    char* ws = (char*)d_ws;
    const size_t MB = 1u << 20;
    // Transient region (0..72 MB):
    //   xb@0 (8, dead after QKV), wqkvb@8 (6, dead after QKV),
    //   qkvb@14 (24, dead after attn), cvb@64 (8, dead after proj),
    //   pp@0 (64, proj partials, alias xb/wqkvb/qkvb; dead after LN1),
    //   qpart@0 (64, FFN2 partials, alias pp; dead after LN2)
    u16*   xb    = (u16*)  (ws + 0 * MB);
    u16*   wqkvb = (u16*)  (ws + 8 * MB);
    u16*   qkvb  = (u16*)  (ws + 14 * MB);
    u16*   cvb   = (u16*)  (ws + 64 * MB);
    float* pp    = (float*)(ws + 0 * MB);
    float* qpart = (float*)(ws + 0 * MB);
    // Persistent region (72..147 MB):
    u16*   wob   = (u16*)  (ws + 72 * MB);
    u16*   w1b   = (u16*)  (ws + 74 * MB);
    u16*   w2b   = (u16*)  (ws + 82 * MB);
    float* bqkv  = (float*)(ws + 90 * MB);
    float* mbias = (float*)(ws + 90 * MB + 65536);
    float* hdf   = (float*)(ws + 91 * MB);
    u16*   hdb   = (u16*)  (ws + 107 * MB);
    u16*   ff1b  = (u16*)  (ws + 115 * MB);   // ends 147 MB

    cvt_all<<<2048, 256, 0, stream>>>(x, wq, wk, wv, wo, w1, w2,
                                      xb, wqkvb, wob, w1b, w2b);
    prep_misc<<<28, 256, 0, stream>>>(bq, bk, bv, mask, bqkv, mbias);

    // fused QKV projection: [4096,3072,1024] on 256x256 8-phase
    gemm256_bt<0><<<dim3(M_ / 256, 3 * D_ / 256, 1), 512, 0, stream>>>(
        xb, wqkvb, bqkv, qkvb, nullptr, 3 * D_, D_);

    // attention: 8 waves, 128 q-rows per block
    attn_kernel<<<dim3(S_ / 128, B_ * H_), 512, 0, stream>>>(qkvb, mbias, cvb);

    // output projection: [4096,1024,1024] split-K4 on 256x256 -> pp[0..3]
    gemm256_bt<1><<<dim3(M_ / 256, D_ / 256, 4), 512, 0, stream>>>(
        cvb, wob, bo, nullptr, pp, D_, D_);

    // residual + LN1: hd = LN(x + pp0..pp3)
    ln_kernel<4><<<M_, 256, 0, stream>>>(x, pp, pp + (size_t)M_ * D_,
                                         pp + 2 * (size_t)M_ * D_,
                                         pp + 3 * (size_t)M_ * D_,
                                         g1, b1, hdf, hdb);

    // FFN1 + GELU: [4096,4096,1024] on 256x256 8-phase
    gemm256_bt<2><<<dim3(M_ / 256, DFF_ / 256, 1), 512, 0, stream>>>(
        hdb, w1b, bf1, ff1b, nullptr, DFF_, D_);

    // FFN2: [4096,1024,4096] split-K4 on 256x256 -> qpart[0..3]
    gemm256_bt<1><<<dim3(M_ / 256, D_ / 256, 4), 512, 0, stream>>>(
        ff1b, w2b, bf2, nullptr, qpart, D_, DFF_);

    // residual + LN2 -> out = LN(hdf + q0..q3)
    ln_kernel<4><<<M_, 256, 0, stream>>>(hdf, qpart, qpart + (size_t)M_ * D_,
                                         qpart + 2 * (size_t)M_ * D_,
                                         qpart + 3 * (size_t)M_ * D_,
                                         g2, b2, out, nullptr);
}